// Round 10
// baseline (364.412 us; speedup 1.0000x reference)
//
#include <hip/hip_runtime.h>
#include <hip/hip_bf16.h>

#define B_ 4
#define S_ 2048
#define D_ 1024
#define H_ 16
#define NEGV (-100000.0f)
#define L2E 1.4426950408889634f

typedef __attribute__((ext_vector_type(8))) short short8;
typedef __attribute__((ext_vector_type(4))) float f32x4;
typedef _Float16 hf2 __attribute__((ext_vector_type(2)));
typedef unsigned short us;
typedef unsigned long long u64;

// f32 -> f16 RTNE
__device__ __forceinline__ us f2h(float f) {
  union { _Float16 h; us u; } c;
  c.h = (_Float16)f;
  return c.u;
}
__device__ __forceinline__ float exp2a(float x) {
  float r;
  asm("v_exp_f32 %0, %1" : "=v"(r) : "v"(x));
  return r;
}

// ---------------- mask dtype detection --------------------------------------
__global__ void detect_mask_kernel(const int* __restrict__ mi, int* __restrict__ flag) {
  int t = threadIdx.x;
  bool bad = false;
  for (int i = t; i < 16384; i += 64) {
    int v = mi[i];
    bad = bad || (v != 0 && v != 1);
  }
  unsigned long long any = __ballot(bad);
  if (t == 0) flag[0] = (any != 0ull) ? 1 : 0;  // 1 => byte mask, 0 => int32 mask
}

// ---------------- bit-pack the mask (both dtypes) ---------------------------
__global__ __launch_bounds__(256) void pack_mask(const void* __restrict__ maskp,
                                                 const int* __restrict__ flag,
                                                 unsigned* __restrict__ pk) {
  int w = blockIdx.x * 256 + threadIdx.x;  // word index over B*S*S/32
  unsigned bits = 0;
  if (flag[0]) {
    const uint4* p = (const uint4*)((const unsigned char*)maskp + (size_t)w * 32);
#pragma unroll
    for (int q = 0; q < 2; ++q) {
      uint4 v = p[q];
      unsigned vv[4] = {v.x, v.y, v.z, v.w};
#pragma unroll
      for (int e = 0; e < 4; ++e) {
        unsigned byte4 = vv[e];
#pragma unroll
        for (int bb = 0; bb < 4; ++bb)
          bits |= (unsigned)(((byte4 >> (8 * bb)) & 0xffu) != 0) << (q * 16 + e * 4 + bb);
      }
    }
  } else {
    const uint4* p = (const uint4*)((const int*)maskp + (size_t)w * 32);
#pragma unroll
    for (int q = 0; q < 8; ++q) {
      uint4 v = p[q];
      bits |= (unsigned)(v.x != 0) << (q * 4 + 0);
      bits |= (unsigned)(v.y != 0) << (q * 4 + 1);
      bits |= (unsigned)(v.z != 0) << (q * 4 + 2);
      bits |= (unsigned)(v.w != 0) << (q * 4 + 3);
    }
  }
  pk[w] = bits;
}

// ---------------- f32 -> f16 converts (up to 3 tensors in one launch) -------
__global__ __launch_bounds__(256) void cvt_f16x3(const float* __restrict__ i0,
                                                 const float* __restrict__ i1,
                                                 const float* __restrict__ i2,
                                                 us* __restrict__ o0, us* __restrict__ o1,
                                                 us* __restrict__ o2) {
  int z = blockIdx.x >> 12;  // 4096 blocks per tensor
  int i = (blockIdx.x & 4095) * 256 + threadIdx.x;
  const float* in = z == 0 ? i0 : z == 1 ? i1 : i2;
  us* out = z == 0 ? o0 : z == 1 ? o1 : o2;
  float4 a = ((const float4*)in)[2 * i];
  float4 b = ((const float4*)in)[2 * i + 1];
  us u[8] = {f2h(a.x), f2h(a.y), f2h(a.z), f2h(a.w),
             f2h(b.x), f2h(b.y), f2h(b.z), f2h(b.w)};
  ((uint4*)out)[i] = *(uint4*)u;
}

__global__ __launch_bounds__(256) void cvt_w4(const float* __restrict__ w0,
                                              const float* __restrict__ w1,
                                              const float* __restrict__ w2,
                                              const float* __restrict__ w3,
                                              us* __restrict__ d0, us* __restrict__ d1,
                                              us* __restrict__ d2, us* __restrict__ d3) {
  int which = blockIdx.x >> 9;  // 512 blocks per weight
  int i = (blockIdx.x & 511) * 256 + threadIdx.x;
  const float* w = which == 0 ? w0 : which == 1 ? w1 : which == 2 ? w2 : w3;
  us* d = which == 0 ? d0 : which == 1 ? d1 : which == 2 ? d2 : d3;
  float4 a = ((const float4*)w)[2 * i];
  float4 b = ((const float4*)w)[2 * i + 1];
  us u[8] = {f2h(a.x), f2h(a.y), f2h(a.z), f2h(a.w),
             f2h(b.x), f2h(b.y), f2h(b.z), f2h(b.w)};
  ((uint4*)d)[i] = *(uint4*)u;
}

__device__ __forceinline__ void gload16(const us* g, us* l) {
  __builtin_amdgcn_global_load_lds((const __attribute__((address_space(1))) void*)g,
                                   (__attribute__((address_space(3))) void*)l, 16, 0, 0);
}

// ---------------- deep-pipelined MFMA GEMM: C = A * W^T + bias --------------
// 256x256 tile, BK=32, 8 waves (2Mx4N), 4 LDS buffers (128 KiB), counted vmcnt.
// OMODE 0: fp32 [M][N] out.  OMODE 2: f16 head-split [b][h][s][64].
template <int OMODE>
__global__ __launch_bounds__(512, 1) void gemm256(
    const us* __restrict__ A0, const us* __restrict__ A1, const us* __restrict__ A2,
    const us* __restrict__ Wp0, const us* __restrict__ Wp1, const us* __restrict__ Wp2,
    const float* __restrict__ b0, const float* __restrict__ b1, const float* __restrict__ b2,
    void* __restrict__ C0, void* __restrict__ C1, void* __restrict__ C2,
    int M, int N, int K) {
  // per buffer: A 256x32 f16 (16KB) at us-off 0, B same at us-off 8192
  __shared__ __align__(16) us SM[4][16384];

  const int z = blockIdx.z;
  const us* A = z == 0 ? A0 : z == 1 ? A1 : A2;
  const us* W = z == 0 ? Wp0 : z == 1 ? Wp1 : Wp2;
  const float* bias = z == 0 ? b0 : z == 1 ? b1 : b2;
  void* Cp = z == 0 ? C0 : z == 1 ? C1 : C2;

  const int m0 = blockIdx.x * 256;
  const int n0 = blockIdx.y * 256;
  const int t = threadIdx.x;
  const int w = t >> 6, l = t & 63;
  const int l15 = l & 15, l4 = l >> 4;
  const int wm = w >> 2, wn = w & 3;  // 2 x 4 waves; per-wave C = 128 x 64

  // staging map: tile 256 rows x 32 k (f16). 1024 chunks of 16B; 2 chunks/thread.
  // LDS dest linear; source column-chunk pre-swizzled: g = c4 ^ (row & 3).
  int goff[2];
#pragma unroll
  for (int j = 0; j < 2; ++j) {
    int u = t + j * 512;
    int r = u >> 2, c4 = u & 3;
    int g = c4 ^ (r & 3);
    goff[j] = r * K + g * 8;
  }
  const us* Ag = A + (size_t)m0 * K;
  const us* Wg = W + (size_t)n0 * K;

  f32x4 acc[8][4];
#pragma unroll
  for (int m = 0; m < 8; ++m)
#pragma unroll
    for (int n = 0; n < 4; ++n) acc[m][n] = (f32x4){0.f, 0.f, 0.f, 0.f};

  auto stage = [&](int kt, int bb) {  // 4 gloads/thread: A j0,j1 then B j0,j1
#pragma unroll
    for (int j = 0; j < 2; ++j) {
      int u = t + j * 512;
      gload16(Ag + goff[j] + kt * 32, &SM[bb][u * 8]);
    }
#pragma unroll
    for (int j = 0; j < 2; ++j) {
      int u = t + j * 512;
      gload16(Wg + goff[j] + kt * 32, &SM[bb][8192 + u * 8]);
    }
  };

  auto body = [&](int bb) {
    const char* Ab = (const char*)&SM[bb][0];
    const char* Bb = Ab + 16384;
    short8 bf[4];
#pragma unroll
    for (int n = 0; n < 4; ++n) {
      int row = wn * 64 + n * 16 + l15;
      bf[n] = *(const short8*)(Bb + row * 64 + ((l4 ^ (row & 3)) << 4));
    }
#pragma unroll
    for (int m = 0; m < 8; ++m) {
      int row = wm * 128 + m * 16 + l15;
      short8 af = *(const short8*)(Ab + row * 64 + ((l4 ^ (row & 3)) << 4));
#pragma unroll
      for (int n = 0; n < 4; ++n)
        acc[m][n] = __builtin_amdgcn_mfma_f32_16x16x32_f16(af, bf[n], acc[m][n], 0, 0, 0);
    }
  };

  const int nt = K / 32;  // 32
  stage(0, 0);
  stage(1, 1);
  stage(2, 2);
  // main loop: lands tile t (vmcnt 8 = leave t+1,t+2 in flight), barrier,
  // then re-stage buffer (t+3)&3 (its prior readers finished at iter t-1).
  int tt = 0;
  for (; tt < nt - 3; ++tt) {
    asm volatile("s_waitcnt vmcnt(8)" ::: "memory");
    asm volatile("s_barrier" ::: "memory");
    stage(tt + 3, (tt + 3) & 3);
    body(tt & 3);
  }
  asm volatile("s_waitcnt vmcnt(8)" ::: "memory");
  asm volatile("s_barrier" ::: "memory");
  body(tt & 3);
  ++tt;
  asm volatile("s_waitcnt vmcnt(4)" ::: "memory");
  asm volatile("s_barrier" ::: "memory");
  body(tt & 3);
  ++tt;
  asm volatile("s_waitcnt vmcnt(0)" ::: "memory");
  asm volatile("s_barrier" ::: "memory");
  body(tt & 3);

  float bv[4];
#pragma unroll
  for (int n = 0; n < 4; ++n) bv[n] = bias[n0 + wn * 64 + n * 16 + l15];

#pragma unroll
  for (int m = 0; m < 8; ++m) {
#pragma unroll
    for (int i = 0; i < 4; ++i) {
      int gm = m0 + wm * 128 + m * 16 + l4 * 4 + i;
#pragma unroll
      for (int n = 0; n < 4; ++n) {
        int gn = n0 + wn * 64 + n * 16 + l15;
        float o = acc[m][n][i] + bv[n];
        if constexpr (OMODE == 0) {
          ((float*)Cp)[(size_t)gm * N + gn] = o;
        } else {
          int b = gm >> 11, s = gm & (S_ - 1);
          int hh = gn >> 6, d = gn & 63;
          size_t idx = (((size_t)(b * H_ + hh) << 11) + s) * 64 + d;
          ((us*)Cp)[idx] = f2h(o);
        }
      }
    }
  }
}

// ---------------- transpose per-head V: [bh][s][64] -> [bh][d][S] -----------
__global__ __launch_bounds__(256) void transpose_v(const us* __restrict__ vh,
                                                   us* __restrict__ vt) {
  __shared__ us Ts[64][72];
  int blk = blockIdx.x;  // bh*32 + stile
  int bh = blk >> 5, s0 = (blk & 31) << 6;
  int t = threadIdx.x;
#pragma unroll
  for (int p = 0; p < 2; ++p) {
    int c = t + p * 256;
    int rs = c >> 3, c8 = c & 7;
    *(uint4*)&Ts[rs][c8 * 8] = *(const uint4*)(vh + ((size_t)bh * S_ + s0 + rs) * 64 + c8 * 8);
  }
  __syncthreads();
#pragma unroll
  for (int p = 0; p < 2; ++p) {
    int c = t + p * 256;
    int rd = c >> 3, s8 = c & 7;
    union { us u[8]; uint4 v; } tmp;
#pragma unroll
    for (int e = 0; e < 8; ++e) tmp.u[e] = Ts[s8 * 8 + e][rd];
    *(uint4*)(vt + ((size_t)bh * 64 + rd) * S_ + s0 + s8 * 8) = tmp.v;
  }
}

// ---------------- MFMA flash attention (fp16, swapped-S^T, 2-phase) ---------
__device__ __forceinline__ int swz(int row, int bc) {  // [64][64] f16 tile, XOR swz
  return (row << 7) + (bc ^ ((row & 7) << 4));
}

__global__ __launch_bounds__(512) void attn_mfma(
    const us* __restrict__ qh, const us* __restrict__ kh,
    const us* __restrict__ vt, const unsigned* __restrict__ pk,
    us* __restrict__ xout) {
  __shared__ __align__(16) us Ks[2][4096];  // [64 k][64 d] f16, XOR-swizzled
  __shared__ __align__(16) us Vs[2][4096];  // [64 d][64 k]
  __shared__ __align__(16) char Ps[16384];  // [128 q][64 k] f16 (wave-private rows)
  __shared__ __align__(16) float MLutF[64]; // nibble -> f32x4 additive mask

  const int blk = ((blockIdx.x & 7) << 7) + (blockIdx.x >> 3);  // XCD swizzle
  const int bh = blk >> 4;
  const int q0 = (blk & 15) << 7;
  const int b = bh >> 4, h = bh & (H_ - 1);
  const int t = threadIdx.x;
  const int w = t >> 6, l = t & 63;
  const int l15 = l & 15, l4 = l >> 4;

  short8 qf[2];
  {
    const size_t qbase = ((size_t)bh * S_ + q0 + 16 * w + l15) * 64 + l4 * 8;
    qf[0] = *(const short8*)(qh + qbase);
    qf[1] = *(const short8*)(qh + qbase + 32);
  }

  f32x4 accO[4];
#pragma unroll
  for (int jd = 0; jd < 4; ++jd) accO[jd] = (f32x4){0.f, 0.f, 0.f, 0.f};
  float m_i = -1e30f, l_p = 0.f;  // per-lane: query l15's running max / partial sum

  const int r_st = t >> 3, c_st = (t & 7) ^ ((t >> 3) & 7);
  const us* kh_src = kh + ((size_t)bh * S_ + r_st) * 64 + c_st * 8;
  const us* vt_src = vt + ((size_t)bh * 64 + r_st) * S_ + c_st * 8;

  auto stage = [&](int k0, int bb) {
    gload16(kh_src + (size_t)k0 * 64, &Ks[bb][t * 8]);
    gload16(vt_src + k0, &Vs[bb][t * 8]);
  };

  if (t < 64) MLutF[t] = (((t >> 2) >> (t & 3)) & 1) ? NEGV : 0.f;
  stage(0, 0);
  __syncthreads();
  int cur = 0;

  char* Pw = Ps + w * 2048;     // wave-private 16 rows
  const int prowb = l15 * 128;  // row byte offset
  const int rr7 = l15 & 7;
  const int bhalf = l4 >> 1;
  const int wsub = (l4 & 1) * 8;
  const unsigned* pb = pk + ((size_t)b * S_ + q0 + 16 * w + l15) * (S_ / 32);

  for (int k0 = 0; k0 < S_; k0 += 64) {
    uint2 mw = *(const uint2*)(pb + (k0 >> 5));
    if (k0 + 64 < S_) stage(k0 + 64, cur ^ 1);

    const char* KT = (const char*)Ks[cur];
    const char* VT = (const char*)Vs[cur];

    // ---- S^T = K · Q^T : lane holds S[key = 16j+4*l4+i][q = l15] ----
    __builtin_amdgcn_s_setprio(1);
    f32x4 sj[4];
#pragma unroll
    for (int j = 0; j < 4; ++j) {
      f32x4 s = {0.f, 0.f, 0.f, 0.f};
#pragma unroll
      for (int c = 0; c < 2; ++c) {
        short8 kf = *(const short8*)(KT + swz(l15 + 16 * j, l4 * 16 + 64 * c));
        s = __builtin_amdgcn_mfma_f32_16x16x32_f16(kf, qf[c], s, 0, 0, 0);
      }
      sj[j] = s;
    }
    __builtin_amdgcn_s_setprio(0);

    // ---- mask via f32x4 LDS LUT (nibble-indexed additive {0, NEG}) ----
#pragma unroll
    for (int j = 0; j < 4; ++j) {
      unsigned wrd = (j < 2) ? mw.x : mw.y;
      unsigned nib = (wrd >> (((j & 1) << 4) + (l4 << 2))) & 0xFu;
      f32x4 lv = *(const f32x4*)&MLutF[nib << 2];
      sj[j] = sj[j] + lv;
    }

    // ---- lane-local max (max3-friendly nesting) + 2 shuffles ----
    float c0 = fmaxf(fmaxf(sj[0][0], sj[0][1]), sj[0][2]);
    float c1 = fmaxf(fmaxf(sj[0][3], sj[1][0]), sj[1][1]);
    float c2 = fmaxf(fmaxf(sj[1][2], sj[1][3]), sj[2][0]);
    float c3 = fmaxf(fmaxf(sj[2][1], sj[2][2]), sj[2][3]);
    float c4 = fmaxf(fmaxf(sj[3][0], sj[3][1]), sj[3][2]);
    float tm = fmaxf(fmaxf(fmaxf(c0, c1), c2), fmaxf(fmaxf(c3, c4), sj[3][3]));
    tm = fmaxf(tm, __shfl_xor(tm, 16));
    tm = fmaxf(tm, __shfl_xor(tm, 32));

    // ---- defer-max rescale (rare, wave-uniform) ----
    if (__any(tm - m_i > 8.0f)) {
      float mnew = fmaxf(m_i, tm);
      float scl = exp2a((m_i - mnew) * L2E);
      l_p *= scl;
      m_i = mnew;
      float sr0 = __shfl(scl, 4 * l4 + 0);
      float sr1 = __shfl(scl, 4 * l4 + 1);
      float sr2 = __shfl(scl, 4 * l4 + 2);
      float sr3 = __shfl(scl, 4 * l4 + 3);
#pragma unroll
      for (int jd = 0; jd < 4; ++jd) {
        accO[jd][0] *= sr0; accO[jd][1] *= sr1;
        accO[jd][2] *= sr2; accO[jd][3] *= sr3;
      }
    }

    // ---- exp (exp2-folded, f32) + pack f16 + 4x b64 P writes + pk l-sum ----
    float ml2 = m_i * L2E;
    hf2 acc2;
    acc2.x = (_Float16)0.f;
    acc2.y = (_Float16)0.f;
#pragma unroll
    for (int j = 0; j < 4; ++j) {
      float p0 = exp2a(fmaf(sj[j][0], L2E, -ml2));
      float p1 = exp2a(fmaf(sj[j][1], L2E, -ml2));
      float p2 = exp2a(fmaf(sj[j][2], L2E, -ml2));
      float p3 = exp2a(fmaf(sj[j][3], L2E, -ml2));
      unsigned d0, d1;
      asm("v_cvt_pkrtz_f16_f32 %0, %1, %2" : "=v"(d0) : "v"(p0), "v"(p1));
      asm("v_cvt_pkrtz_f16_f32 %0, %1, %2" : "=v"(d1) : "v"(p2), "v"(p3));
      union { unsigned u; hf2 h; } c0u, c1u;
      c0u.u = d0;
      c1u.u = d1;
      acc2 = acc2 + c0u.h + c1u.h;
      int chunk = ((j << 1) | bhalf) ^ rr7;
      *(u64*)(Pw + prowb + (chunk << 4) + wsub) = (u64)d0 | ((u64)d1 << 32);
    }
    l_p += (float)acc2.x + (float)acc2.y;
    // in-wave ordering: P writes land before A-frag reads
    asm volatile("s_waitcnt lgkmcnt(0)" ::: "memory");
    __builtin_amdgcn_sched_barrier(0);

    // ---- PV ----
    __builtin_amdgcn_s_setprio(1);
#pragma unroll
    for (int kc = 0; kc < 2; ++kc) {
      int chR = (4 * kc + l4) ^ rr7;
      short8 pa = *(const short8*)(Pw + prowb + (chR << 4));
#pragma unroll
      for (int jd = 0; jd < 4; ++jd) {
        short8 vb = *(const short8*)(VT + swz(l15 + 16 * jd, l4 * 16 + 64 * kc));
        accO[jd] = __builtin_amdgcn_mfma_f32_16x16x32_f16(pa, vb, accO[jd], 0, 0, 0);
      }
    }
    __builtin_amdgcn_s_setprio(0);
    __syncthreads();
    cur ^= 1;
  }

  // epilogue: reduce partial l across l4 groups, redistribute to accO rows
  float lr = l_p;
  lr += __shfl_xor(lr, 16);
  lr += __shfl_xor(lr, 32);
  float inv0 = 1.f / __shfl(lr, 4 * l4 + 0);
  float inv1 = 1.f / __shfl(lr, 4 * l4 + 1);
  float inv2 = 1.f / __shfl(lr, 4 * l4 + 2);
  float inv3 = 1.f / __shfl(lr, 4 * l4 + 3);
  float invs[4] = {inv0, inv1, inv2, inv3};
#pragma unroll
  for (int i = 0; i < 4; ++i) {
    int row = q0 + 16 * w + l4 * 4 + i;
    size_t obase = ((size_t)b * S_ + row) * D_ + h * 64 + l15;
#pragma unroll
    for (int jd = 0; jd < 4; ++jd) xout[obase + 16 * jd] = f2h(accO[jd][i] * invs[i]);
  }
}

extern "C" void kernel_launch(void* const* d_in, const int* in_sizes, int n_in,
                              void* d_out, int out_size, void* d_ws, size_t ws_size,
                              hipStream_t stream) {
  const float* q = (const float*)d_in[0];
  const float* k = (const float*)d_in[1];
  const float* v = (const float*)d_in[2];
  const void* mask = d_in[3];
  const float* wq_w = (const float*)d_in[4];
  const float* wq_b = (const float*)d_in[5];
  const float* wk_w = (const float*)d_in[6];
  const float* wk_b = (const float*)d_in[7];
  const float* wv_w = (const float*)d_in[8];
  const float* wv_b = (const float*)d_in[9];
  const float* wo_w = (const float*)d_in[10];
  const float* wo_b = (const float*)d_in[11];

  const size_t NE = (size_t)B_ * S_ * D_;  // 8M elems
  const size_t NW = (size_t)D_ * D_;       // 1M elems
  const size_t PKB = (size_t)(B_ * S_ * (S_ / 32)) * 4;  // 2MB
  char* ws = (char*)d_ws;
  int* flag = (int*)ws;
  unsigned* pkb = (unsigned*)(ws + 256);
  us* base = (us*)(ws + 256 + PKB);

  detect_mask_kernel<<<1, 64, 0, stream>>>((const int*)mask, flag);
  pack_mask<<<2048, 256, 0, stream>>>(mask, flag, pkb);

  dim3 g3(32, 4, 3);  // 8192/256, 1024/256
  dim3 g2(32, 4, 2);
  dim3 g1(32, 4, 1);

  const size_t fused_need = 256 + PKB + 6 * NE * 2 + 4 * NW * 2;
  if (ws_size >= fused_need) {
    us* A0 = base;          // q f16 -> later vt
    us* A1 = A0 + NE;       // k f16 -> later xo
    us* A2 = A1 + NE;       // v f16
    us* A3 = A2 + NE;       // qh
    us* A4 = A3 + NE;       // kh
    us* A5 = A4 + NE;       // vh
    us* W0 = A5 + NE;
    us* W1 = W0 + NW;
    us* W2 = W1 + NW;
    us* W3 = W2 + NW;
    cvt_w4<<<2048, 256, 0, stream>>>(wq_w, wk_w, wv_w, wo_w, W0, W1, W2, W3);
    cvt_f16x3<<<3 * 4096, 256, 0, stream>>>(q, k, v, A0, A1, A2);
    gemm256<2><<<g3, 512, 0, stream>>>(A0, A1, A2, W0, W1, W2, wq_b, wk_b, wv_b,
                                       A3, A4, A5, B_ * S_, D_, D_);
    transpose_v<<<2048, 256, 0, stream>>>(A5, A0);  // vt in A0
    attn_mfma<<<1024, 512, 0, stream>>>(A3, A4, A0, pkb, A1);  // xo in A1
    gemm256<0><<<g1, 512, 0, stream>>>(A1, A1, A1, W3, W3, W3, wo_b, wo_b, wo_b,
                                       d_out, d_out, d_out, B_ * S_, D_, D_);
  } else {
    // sequential 5-buffer plan
    us* A0 = base;
    us* A1 = A0 + NE;
    us* A2 = A1 + NE;  // qh
    us* A3 = A2 + NE;  // kh
    us* A4 = A3 + NE;  // vt
    us* W0 = A4 + NE;
    us* W1 = W0 + NW;
    us* W2 = W1 + NW;
    us* W3 = W2 + NW;
    cvt_w4<<<2048, 256, 0, stream>>>(wq_w, wk_w, wv_w, wo_w, W0, W1, W2, W3);
    cvt_f16x3<<<2 * 4096, 256, 0, stream>>>(q, k, nullptr, A0, A1, nullptr);
    gemm256<2><<<g2, 512, 0, stream>>>(A0, A1, nullptr, W0, W1, nullptr, wq_b, wk_b, nullptr,
                                       A2, A3, nullptr, B_ * S_, D_, D_);
    cvt_f16x3<<<4096, 256, 0, stream>>>(v, nullptr, nullptr, A0, nullptr, nullptr);
    gemm256<2><<<g1, 512, 0, stream>>>(A0, nullptr, nullptr, W2, nullptr, nullptr,
                                       wv_b, nullptr, nullptr, A1, nullptr, nullptr,
                                       B_ * S_, D_, D_);
    transpose_v<<<2048, 256, 0, stream>>>(A1, A4);
    attn_mfma<<<1024, 512, 0, stream>>>(A2, A3, A4, pkb, A0);  // xo in A0
    gemm256<0><<<g1, 512, 0, stream>>>(A0, nullptr, nullptr, W3, nullptr, nullptr,
                                       wo_b, nullptr, nullptr, d_out, nullptr, nullptr,
                                       B_ * S_, D_, D_);
  }
}

// Round 11
// 359.490 us; speedup vs baseline: 1.0137x; 1.0137x over previous
//
#include <hip/hip_runtime.h>
#include <hip/hip_bf16.h>

#define B_ 4
#define S_ 2048
#define D_ 1024
#define H_ 16
#define NEGV (-100000.0f)
#define L2E 1.4426950408889634f

typedef __attribute__((ext_vector_type(8))) short short8;
typedef __attribute__((ext_vector_type(4))) float f32x4;
typedef _Float16 hf2 __attribute__((ext_vector_type(2)));
typedef unsigned short us;
typedef unsigned long long u64;

// f32 -> f16 RTNE
__device__ __forceinline__ us f2h(float f) {
  union { _Float16 h; us u; } c;
  c.h = (_Float16)f;
  return c.u;
}
__device__ __forceinline__ float exp2a(float x) {
  float r;
  asm("v_exp_f32 %0, %1" : "=v"(r) : "v"(x));
  return r;
}

// ---------------- standalone prep kernels (fallback path) -------------------
__global__ void detect_mask_kernel(const int* __restrict__ mi, int* __restrict__ flag) {
  int t = threadIdx.x;
  bool bad = false;
  for (int i = t; i < 16384; i += 64) {
    int v = mi[i];
    bad = bad || (v != 0 && v != 1);
  }
  unsigned long long any = __ballot(bad);
  if (t == 0) flag[0] = (any != 0ull) ? 1 : 0;  // 1 => byte mask, 0 => int32 mask
}

__device__ __forceinline__ unsigned pack_words(const void* maskp, int mode, int w) {
  unsigned bits = 0;
  if (mode) {
    const uint4* p = (const uint4*)((const unsigned char*)maskp + (size_t)w * 32);
#pragma unroll
    for (int q = 0; q < 2; ++q) {
      uint4 v = p[q];
      unsigned vv[4] = {v.x, v.y, v.z, v.w};
#pragma unroll
      for (int e = 0; e < 4; ++e) {
        unsigned byte4 = vv[e];
#pragma unroll
        for (int bb = 0; bb < 4; ++bb)
          bits |= (unsigned)(((byte4 >> (8 * bb)) & 0xffu) != 0) << (q * 16 + e * 4 + bb);
      }
    }
  } else {
    const uint4* p = (const uint4*)((const int*)maskp + (size_t)w * 32);
#pragma unroll
    for (int q = 0; q < 8; ++q) {
      uint4 v = p[q];
      bits |= (unsigned)(v.x != 0) << (q * 4 + 0);
      bits |= (unsigned)(v.y != 0) << (q * 4 + 1);
      bits |= (unsigned)(v.z != 0) << (q * 4 + 2);
      bits |= (unsigned)(v.w != 0) << (q * 4 + 3);
    }
  }
  return bits;
}

__global__ __launch_bounds__(256) void pack_mask(const void* __restrict__ maskp,
                                                 const int* __restrict__ flag,
                                                 unsigned* __restrict__ pk) {
  int w = blockIdx.x * 256 + threadIdx.x;
  pk[w] = pack_words(maskp, flag[0], w);
}

__device__ __forceinline__ void cvt8(const float* in, us* out, int i) {
  float4 a = ((const float4*)in)[2 * i];
  float4 b = ((const float4*)in)[2 * i + 1];
  us u[8] = {f2h(a.x), f2h(a.y), f2h(a.z), f2h(a.w),
             f2h(b.x), f2h(b.y), f2h(b.z), f2h(b.w)};
  ((uint4*)out)[i] = *(uint4*)u;
}

__global__ __launch_bounds__(256) void cvt_f16x3(const float* __restrict__ i0,
                                                 const float* __restrict__ i1,
                                                 const float* __restrict__ i2,
                                                 us* __restrict__ o0, us* __restrict__ o1,
                                                 us* __restrict__ o2) {
  int z = blockIdx.x >> 12;
  int i = (blockIdx.x & 4095) * 256 + threadIdx.x;
  const float* in = z == 0 ? i0 : z == 1 ? i1 : i2;
  us* out = z == 0 ? o0 : z == 1 ? o1 : o2;
  cvt8(in, out, i);
}

// ---------------- merged prep (fused path): weights + detect ----------------
__global__ __launch_bounds__(256) void prep_w(
    const float* __restrict__ w0, const float* __restrict__ w1,
    const float* __restrict__ w2, const float* __restrict__ w3,
    us* __restrict__ d0, us* __restrict__ d1, us* __restrict__ d2, us* __restrict__ d3,
    const int* __restrict__ mi, int* __restrict__ flag) {
  if (blockIdx.x == 2048) {
    int t = threadIdx.x;
    if (t >= 64) return;
    bool bad = false;
    for (int i = t; i < 16384; i += 64) {
      int v = mi[i];
      bad = bad || (v != 0 && v != 1);
    }
    unsigned long long any = __ballot(bad);
    if (t == 0) flag[0] = (any != 0ull) ? 1 : 0;
    return;
  }
  int which = blockIdx.x >> 9;
  int i = (blockIdx.x & 511) * 256 + threadIdx.x;
  const float* w = which == 0 ? w0 : which == 1 ? w1 : which == 2 ? w2 : w3;
  us* d = which == 0 ? d0 : which == 1 ? d1 : which == 2 ? d2 : d3;
  cvt8(w, d, i);
}

// ---------------- merged prep: mask-pack + q/k/v convert --------------------
__global__ __launch_bounds__(256) void prep_in(
    const void* __restrict__ maskp, const int* __restrict__ flag, unsigned* __restrict__ pk,
    const float* __restrict__ i0, const float* __restrict__ i1, const float* __restrict__ i2,
    us* __restrict__ o0, us* __restrict__ o1, us* __restrict__ o2) {
  if (blockIdx.x < 2048) {
    int w = blockIdx.x * 256 + threadIdx.x;
    pk[w] = pack_words(maskp, flag[0], w);
    return;
  }
  int c = blockIdx.x - 2048;
  int z = c >> 12;
  int i = (c & 4095) * 256 + threadIdx.x;
  const float* in = z == 0 ? i0 : z == 1 ? i1 : i2;
  us* out = z == 0 ? o0 : z == 1 ? o1 : o2;
  cvt8(in, out, i);
}

__device__ __forceinline__ void gload16(const us* g, us* l) {
  __builtin_amdgcn_global_load_lds((const __attribute__((address_space(1))) void*)g,
                                   (__attribute__((address_space(3))) void*)l, 16, 0, 0);
}

// ---------------- deep-pipelined MFMA GEMM: C = A * W^T + bias --------------
// 128x128 tile, BK=32, 4 waves (2Mx2N), 4 LDS buffers (64 KiB -> 2 blocks/CU),
// counted vmcnt (never 0 in-loop), raw s_barrier (no vmcnt-draining syncthreads).
// OMODE 0: fp32 [M][N].  OMODE 2: f16 head-split [b][h][s][64];
//   z == trans_z: epilogue writes V^T layout [bh][d][S] instead.
template <int OMODE>
__global__ __launch_bounds__(256, 2) void gemm_dp(
    const us* __restrict__ A0, const us* __restrict__ A1, const us* __restrict__ A2,
    const us* __restrict__ Wp0, const us* __restrict__ Wp1, const us* __restrict__ Wp2,
    const float* __restrict__ b0, const float* __restrict__ b1, const float* __restrict__ b2,
    void* __restrict__ C0, void* __restrict__ C1, void* __restrict__ C2,
    int M, int N, int K, int trans_z) {
  // per buffer (8192 us = 16KB): A[128x32 f16] @0, B[128x32 f16] @4096
  __shared__ __align__(16) us SM[4][8192];

  const int z = blockIdx.z;
  const us* A = z == 0 ? A0 : z == 1 ? A1 : A2;
  const us* W = z == 0 ? Wp0 : z == 1 ? Wp1 : Wp2;
  const float* bias = z == 0 ? b0 : z == 1 ? b1 : b2;
  void* Cp = z == 0 ? C0 : z == 1 ? C1 : C2;

  const int m0 = blockIdx.x * 128;
  const int n0 = blockIdx.y * 128;
  const int t = threadIdx.x;
  const int w = t >> 6, l = t & 63;
  const int l15 = l & 15, l4 = l >> 4;
  const int wm = w >> 1, wn = w & 1;  // 2x2 waves; per-wave C = 64 x 64

  // staging: per array 512 chunks of 16B (128 rows x 4 chunks); 2 chunks/thread.
  // LDS dest linear; source column-chunk pre-swizzled: g = c4 ^ (row & 3).
  int goff[2];
#pragma unroll
  for (int j = 0; j < 2; ++j) {
    int u = t + j * 256;
    int r = u >> 2, c4 = u & 3;
    int g = c4 ^ (r & 3);
    goff[j] = r * K + g * 8;
  }
  const us* Ag = A + (size_t)m0 * K;
  const us* Wg = W + (size_t)n0 * K;

  f32x4 acc[4][4];
#pragma unroll
  for (int m = 0; m < 4; ++m)
#pragma unroll
    for (int n = 0; n < 4; ++n) acc[m][n] = (f32x4){0.f, 0.f, 0.f, 0.f};

  auto stage = [&](int kt, int bb) {  // 4 gloads/thread: A j0,j1 then B j0,j1
#pragma unroll
    for (int j = 0; j < 2; ++j) {
      int u = t + j * 256;
      gload16(Ag + goff[j] + kt * 32, &SM[bb][u * 8]);
    }
#pragma unroll
    for (int j = 0; j < 2; ++j) {
      int u = t + j * 256;
      gload16(Wg + goff[j] + kt * 32, &SM[bb][4096 + u * 8]);
    }
  };

  auto body = [&](int bb) {
    const char* Ab = (const char*)&SM[bb][0];
    const char* Bb = Ab + 8192;
    short8 bf[4], af[4];
#pragma unroll
    for (int n = 0; n < 4; ++n) {
      int row = wn * 64 + n * 16 + l15;
      bf[n] = *(const short8*)(Bb + row * 64 + ((l4 ^ (row & 3)) << 4));
    }
#pragma unroll
    for (int m = 0; m < 4; ++m) {
      int row = wm * 64 + m * 16 + l15;
      af[m] = *(const short8*)(Ab + row * 64 + ((l4 ^ (row & 3)) << 4));
    }
#pragma unroll
    for (int m = 0; m < 4; ++m)
#pragma unroll
      for (int n = 0; n < 4; ++n)
        acc[m][n] = __builtin_amdgcn_mfma_f32_16x16x32_f16(af[m], bf[n], acc[m][n], 0, 0, 0);
  };

  const int nt = K / 32;  // 32
  stage(0, 0);
  stage(1, 1);
  stage(2, 2);
  int tt = 0;
  for (; tt < nt - 3; ++tt) {
    asm volatile("s_waitcnt vmcnt(8)" ::: "memory");  // tile tt landed
    asm volatile("s_barrier" ::: "memory");
    stage(tt + 3, (tt + 3) & 3);  // overwrites buffer last read at iter tt-1
    body(tt & 3);
  }
  asm volatile("s_waitcnt vmcnt(8)" ::: "memory");
  asm volatile("s_barrier" ::: "memory");
  body(tt & 3);
  ++tt;
  asm volatile("s_waitcnt vmcnt(4)" ::: "memory");
  asm volatile("s_barrier" ::: "memory");
  body(tt & 3);
  ++tt;
  asm volatile("s_waitcnt vmcnt(0)" ::: "memory");
  asm volatile("s_barrier" ::: "memory");
  body(tt & 3);

  float bv[4];
#pragma unroll
  for (int n = 0; n < 4; ++n) bv[n] = bias[n0 + wn * 64 + n * 16 + l15];

  if (OMODE == 2 && z == trans_z) {
    // ---- transposed epilogue: write V^T [bh][d][S] via LDS [128 col][136 s] ----
    __syncthreads();  // all waves done reading SM buffers
    us* T = (us*)SM;
#pragma unroll
    for (int n = 0; n < 4; ++n) {
      int col = wn * 64 + n * 16 + l15;
#pragma unroll
      for (int m = 0; m < 4; ++m) {
        int sr = wm * 64 + m * 16 + l4 * 4;
#pragma unroll
        for (int ip = 0; ip < 2; ++ip) {
          us h0 = f2h(acc[m][n][2 * ip] + bv[n]);
          us h1 = f2h(acc[m][n][2 * ip + 1] + bv[n]);
          *(unsigned*)&T[col * 136 + sr + 2 * ip] = (unsigned)h0 | ((unsigned)h1 << 16);
        }
      }
    }
    __syncthreads();
    const int b = m0 >> 11, sb = m0 & (S_ - 1);
    const int colr = t >> 1, sc = (t & 1) << 6;
    const int hh = (n0 >> 6) + (colr >> 6), d = colr & 63;
    us* dst = (us*)Cp + (((size_t)(b * H_ + hh) << 6) + (size_t)d) * S_ + sb + sc;
#pragma unroll
    for (int p = 0; p < 8; ++p)
      *(uint4*)(dst + p * 8) = *(const uint4*)&T[colr * 136 + sc + p * 8];
    return;
  }

#pragma unroll
  for (int m = 0; m < 4; ++m) {
#pragma unroll
    for (int i = 0; i < 4; ++i) {
      int gm = m0 + wm * 64 + m * 16 + l4 * 4 + i;
#pragma unroll
      for (int n = 0; n < 4; ++n) {
        int gn = n0 + wn * 64 + n * 16 + l15;
        float o = acc[m][n][i] + bv[n];
        if constexpr (OMODE == 0) {
          ((float*)Cp)[(size_t)gm * N + gn] = o;
        } else {
          int b = gm >> 11, s = gm & (S_ - 1);
          int hh = gn >> 6, d = gn & 63;
          size_t idx = (((size_t)(b * H_ + hh) << 11) + s) * 64 + d;
          ((us*)Cp)[idx] = f2h(o);
        }
      }
    }
  }
}

// ---------------- MFMA flash attention (fp16, swapped-S^T, 2-phase) ---------
__device__ __forceinline__ int swz(int row, int bc) {  // [64][64] f16 tile, XOR swz
  return (row << 7) + (bc ^ ((row & 7) << 4));
}

__global__ __launch_bounds__(512) void attn_mfma(
    const us* __restrict__ qh, const us* __restrict__ kh,
    const us* __restrict__ vt, const unsigned* __restrict__ pk,
    us* __restrict__ xout) {
  __shared__ __align__(16) us Ks[2][4096];  // [64 k][64 d] f16, XOR-swizzled
  __shared__ __align__(16) us Vs[2][4096];  // [64 d][64 k]
  __shared__ __align__(16) char Ps[16384];  // [128 q][64 k] f16 (wave-private rows)
  __shared__ __align__(16) float MLutF[64]; // nibble -> f32x4 additive mask

  const int blk = ((blockIdx.x & 7) << 7) + (blockIdx.x >> 3);  // XCD swizzle
  const int bh = blk >> 4;
  const int q0 = (blk & 15) << 7;
  const int b = bh >> 4, h = bh & (H_ - 1);
  const int t = threadIdx.x;
  const int w = t >> 6, l = t & 63;
  const int l15 = l & 15, l4 = l >> 4;

  short8 qf[2];
  {
    const size_t qbase = ((size_t)bh * S_ + q0 + 16 * w + l15) * 64 + l4 * 8;
    qf[0] = *(const short8*)(qh + qbase);
    qf[1] = *(const short8*)(qh + qbase + 32);
  }

  f32x4 accO[4];
#pragma unroll
  for (int jd = 0; jd < 4; ++jd) accO[jd] = (f32x4){0.f, 0.f, 0.f, 0.f};
  float m_i = -1e30f, l_p = 0.f;  // per-lane: query l15's running max / partial sum

  const int r_st = t >> 3, c_st = (t & 7) ^ ((t >> 3) & 7);
  const us* kh_src = kh + ((size_t)bh * S_ + r_st) * 64 + c_st * 8;
  const us* vt_src = vt + ((size_t)bh * 64 + r_st) * S_ + c_st * 8;

  auto stage = [&](int k0, int bb) {
    gload16(kh_src + (size_t)k0 * 64, &Ks[bb][t * 8]);
    gload16(vt_src + k0, &Vs[bb][t * 8]);
  };

  if (t < 64) MLutF[t] = (((t >> 2) >> (t & 3)) & 1) ? NEGV : 0.f;
  stage(0, 0);
  __syncthreads();
  int cur = 0;

  char* Pw = Ps + w * 2048;     // wave-private 16 rows
  const int prowb = l15 * 128;  // row byte offset
  const int rr7 = l15 & 7;
  const int bhalf = l4 >> 1;
  const int wsub = (l4 & 1) * 8;
  const unsigned* pb = pk + ((size_t)b * S_ + q0 + 16 * w + l15) * (S_ / 32);

  for (int k0 = 0; k0 < S_; k0 += 64) {
    uint2 mw = *(const uint2*)(pb + (k0 >> 5));
    if (k0 + 64 < S_) stage(k0 + 64, cur ^ 1);

    const char* KT = (const char*)Ks[cur];
    const char* VT = (const char*)Vs[cur];

    // ---- S^T = K · Q^T : lane holds S[key = 16j+4*l4+i][q = l15] ----
    __builtin_amdgcn_s_setprio(1);
    f32x4 sj[4];
#pragma unroll
    for (int j = 0; j < 4; ++j) {
      f32x4 s = {0.f, 0.f, 0.f, 0.f};
#pragma unroll
      for (int c = 0; c < 2; ++c) {
        short8 kf = *(const short8*)(KT + swz(l15 + 16 * j, l4 * 16 + 64 * c));
        s = __builtin_amdgcn_mfma_f32_16x16x32_f16(kf, qf[c], s, 0, 0, 0);
      }
      sj[j] = s;
    }
    __builtin_amdgcn_s_setprio(0);

    // ---- mask via f32x4 LDS LUT (nibble-indexed additive {0, NEG}) ----
#pragma unroll
    for (int j = 0; j < 4; ++j) {
      unsigned wrd = (j < 2) ? mw.x : mw.y;
      unsigned nib = (wrd >> (((j & 1) << 4) + (l4 << 2))) & 0xFu;
      f32x4 lv = *(const f32x4*)&MLutF[nib << 2];
      sj[j] = sj[j] + lv;
    }

    // ---- lane-local max (max3-friendly nesting) + 2 shuffles ----
    float c0 = fmaxf(fmaxf(sj[0][0], sj[0][1]), sj[0][2]);
    float c1 = fmaxf(fmaxf(sj[0][3], sj[1][0]), sj[1][1]);
    float c2 = fmaxf(fmaxf(sj[1][2], sj[1][3]), sj[2][0]);
    float c3 = fmaxf(fmaxf(sj[2][1], sj[2][2]), sj[2][3]);
    float c4 = fmaxf(fmaxf(sj[3][0], sj[3][1]), sj[3][2]);
    float tm = fmaxf(fmaxf(fmaxf(c0, c1), c2), fmaxf(fmaxf(c3, c4), sj[3][3]));
    tm = fmaxf(tm, __shfl_xor(tm, 16));
    tm = fmaxf(tm, __shfl_xor(tm, 32));

    // ---- defer-max rescale (rare, wave-uniform) ----
    if (__any(tm - m_i > 8.0f)) {
      float mnew = fmaxf(m_i, tm);
      float scl = exp2a((m_i - mnew) * L2E);
      l_p *= scl;
      m_i = mnew;
      float sr0 = __shfl(scl, 4 * l4 + 0);
      float sr1 = __shfl(scl, 4 * l4 + 1);
      float sr2 = __shfl(scl, 4 * l4 + 2);
      float sr3 = __shfl(scl, 4 * l4 + 3);
#pragma unroll
      for (int jd = 0; jd < 4; ++jd) {
        accO[jd][0] *= sr0; accO[jd][1] *= sr1;
        accO[jd][2] *= sr2; accO[jd][3] *= sr3;
      }
    }

    // ---- exp (exp2-folded, f32) + pack f16 + 4x b64 P writes + pk l-sum ----
    float ml2 = m_i * L2E;
    hf2 acc2;
    acc2.x = (_Float16)0.f;
    acc2.y = (_Float16)0.f;
#pragma unroll
    for (int j = 0; j < 4; ++j) {
      float p0 = exp2a(fmaf(sj[j][0], L2E, -ml2));
      float p1 = exp2a(fmaf(sj[j][1], L2E, -ml2));
      float p2 = exp2a(fmaf(sj[j][2], L2E, -ml2));
      float p3 = exp2a(fmaf(sj[j][3], L2E, -ml2));
      unsigned d0, d1;
      asm("v_cvt_pkrtz_f16_f32 %0, %1, %2" : "=v"(d0) : "v"(p0), "v"(p1));
      asm("v_cvt_pkrtz_f16_f32 %0, %1, %2" : "=v"(d1) : "v"(p2), "v"(p3));
      union { unsigned u; hf2 h; } c0u, c1u;
      c0u.u = d0;
      c1u.u = d1;
      acc2 = acc2 + c0u.h + c1u.h;
      int chunk = ((j << 1) | bhalf) ^ rr7;
      *(u64*)(Pw + prowb + (chunk << 4) + wsub) = (u64)d0 | ((u64)d1 << 32);
    }
    l_p += (float)acc2.x + (float)acc2.y;
    // in-wave ordering: P writes land before A-frag reads
    asm volatile("s_waitcnt lgkmcnt(0)" ::: "memory");
    __builtin_amdgcn_sched_barrier(0);

    // ---- PV ----
    __builtin_amdgcn_s_setprio(1);
#pragma unroll
    for (int kc = 0; kc < 2; ++kc) {
      int chR = (4 * kc + l4) ^ rr7;
      short8 pa = *(const short8*)(Pw + prowb + (chR << 4));
#pragma unroll
      for (int jd = 0; jd < 4; ++jd) {
        short8 vb = *(const short8*)(VT + swz(l15 + 16 * jd, l4 * 16 + 64 * kc));
        accO[jd] = __builtin_amdgcn_mfma_f32_16x16x32_f16(pa, vb, accO[jd], 0, 0, 0);
      }
    }
    __builtin_amdgcn_s_setprio(0);
    __syncthreads();
    cur ^= 1;
  }

  // epilogue: reduce partial l across l4 groups, redistribute to accO rows
  float lr = l_p;
  lr += __shfl_xor(lr, 16);
  lr += __shfl_xor(lr, 32);
  float inv0 = 1.f / __shfl(lr, 4 * l4 + 0);
  float inv1 = 1.f / __shfl(lr, 4 * l4 + 1);
  float inv2 = 1.f / __shfl(lr, 4 * l4 + 2);
  float inv3 = 1.f / __shfl(lr, 4 * l4 + 3);
  float invs[4] = {inv0, inv1, inv2, inv3};
#pragma unroll
  for (int i = 0; i < 4; ++i) {
    int row = q0 + 16 * w + l4 * 4 + i;
    size_t obase = ((size_t)b * S_ + row) * D_ + h * 64 + l15;
#pragma unroll
    for (int jd = 0; jd < 4; ++jd) xout[obase + 16 * jd] = f2h(accO[jd][i] * invs[i]);
  }
}

extern "C" void kernel_launch(void* const* d_in, const int* in_sizes, int n_in,
                              void* d_out, int out_size, void* d_ws, size_t ws_size,
                              hipStream_t stream) {
  const float* q = (const float*)d_in[0];
  const float* k = (const float*)d_in[1];
  const float* v = (const float*)d_in[2];
  const void* mask = d_in[3];
  const float* wq_w = (const float*)d_in[4];
  const float* wq_b = (const float*)d_in[5];
  const float* wk_w = (const float*)d_in[6];
  const float* wk_b = (const float*)d_in[7];
  const float* wv_w = (const float*)d_in[8];
  const float* wv_b = (const float*)d_in[9];
  const float* wo_w = (const float*)d_in[10];
  const float* wo_b = (const float*)d_in[11];

  const size_t NE = (size_t)B_ * S_ * D_;  // 8M elems
  const size_t NW = (size_t)D_ * D_;       // 1M elems
  const size_t PKB = (size_t)(B_ * S_ * (S_ / 32)) * 4;  // 2MB
  char* ws = (char*)d_ws;
  int* flag = (int*)ws;
  unsigned* pkb = (unsigned*)(ws + 256);
  us* base = (us*)(ws + 256 + PKB);

  dim3 g3(64, 8, 3);
  dim3 g2(64, 8, 2);
  dim3 g1(64, 8, 1);

  const size_t fused_need = 256 + PKB + 6 * NE * 2 + 4 * NW * 2;
  if (ws_size >= fused_need) {
    us* A0 = base;          // q f16 -> later xo
    us* A1 = A0 + NE;       // k f16
    us* A2 = A1 + NE;       // v f16
    us* A3 = A2 + NE;       // qh
    us* A4 = A3 + NE;       // kh
    us* A5 = A4 + NE;       // vt
    us* W0 = A5 + NE;
    us* W1 = W0 + NW;
    us* W2 = W1 + NW;
    us* W3 = W2 + NW;
    prep_w<<<2049, 256, 0, stream>>>(wq_w, wk_w, wv_w, wo_w, W0, W1, W2, W3,
                                     (const int*)mask, flag);
    prep_in<<<2048 + 3 * 4096, 256, 0, stream>>>(mask, flag, pkb, q, k, v, A0, A1, A2);
    gemm_dp<2><<<g3, 256, 0, stream>>>(A0, A1, A2, W0, W1, W2, wq_b, wk_b, wv_b,
                                       A3, A4, A5, B_ * S_, D_, D_, 2);
    attn_mfma<<<1024, 512, 0, stream>>>(A3, A4, A5, pkb, A0);  // xo in A0
    gemm_dp<0><<<g1, 256, 0, stream>>>(A0, A0, A0, W3, W3, W3, wo_b, wo_b, wo_b,
                                       d_out, d_out, d_out, B_ * S_, D_, D_, -1);
  } else {
    // sequential 5-buffer plan
    us* A0 = base;
    us* A1 = A0 + NE;
    us* A2 = A1 + NE;  // qh
    us* A3 = A2 + NE;  // kh
    us* A4 = A3 + NE;  // vt
    us* W0 = A4 + NE;
    us* W1 = W0 + NW;
    us* W2 = W1 + NW;
    us* W3 = W2 + NW;
    detect_mask_kernel<<<1, 64, 0, stream>>>((const int*)mask, flag);
    pack_mask<<<2048, 256, 0, stream>>>(mask, flag, pkb);
    prep_w<<<2048, 256, 0, stream>>>(wq_w, wk_w, wv_w, wo_w, W0, W1, W2, W3,
                                     (const int*)mask, flag);
    cvt_f16x3<<<2 * 4096, 256, 0, stream>>>(q, k, nullptr, A0, A1, nullptr);
    gemm_dp<2><<<g2, 256, 0, stream>>>(A0, A1, nullptr, W0, W1, nullptr, wq_b, wk_b, nullptr,
                                       A2, A3, nullptr, B_ * S_, D_, D_, -1);
    cvt_f16x3<<<4096, 256, 0, stream>>>(v, nullptr, nullptr, A0, nullptr, nullptr);
    gemm_dp<2><<<g1, 256, 0, stream>>>(A0, nullptr, nullptr, W2, nullptr, nullptr,
                                       wv_b, nullptr, nullptr, A4, nullptr, nullptr,
                                       B_ * S_, D_, D_, 0);  // V -> vt (transposed)
    attn_mfma<<<1024, 512, 0, stream>>>(A2, A3, A4, pkb, A0);  // xo in A0
    gemm_dp<0><<<g1, 256, 0, stream>>>(A0, nullptr, nullptr, W3, nullptr, nullptr,
                                       wo_b, nullptr, nullptr, d_out, nullptr, nullptr,
                                       B_ * S_, D_, D_, -1);
  }
}

// Round 13
// 348.870 us; speedup vs baseline: 1.0445x; 1.0304x over previous
//
#include <hip/hip_runtime.h>
#include <hip/hip_bf16.h>

#define B_ 4
#define S_ 2048
#define D_ 1024
#define H_ 16
#define NEGV (-100000.0f)
#define L2E 1.4426950408889634f

typedef __attribute__((ext_vector_type(8))) short short8;
typedef __attribute__((ext_vector_type(4))) float f32x4;
typedef _Float16 hf2 __attribute__((ext_vector_type(2)));
typedef unsigned short us;
typedef unsigned long long u64;

// f32 -> f16 RTNE
__device__ __forceinline__ us f2h(float f) {
  union { _Float16 h; us u; } c;
  c.h = (_Float16)f;
  return c.u;
}
__device__ __forceinline__ float exp2a(float x) {
  float r;
  asm("v_exp_f32 %0, %1" : "=v"(r) : "v"(x));
  return r;
}

// ---------------- standalone prep kernels (fallback path) -------------------
__global__ void detect_mask_kernel(const int* __restrict__ mi, int* __restrict__ flag) {
  int t = threadIdx.x;
  bool bad = false;
  for (int i = t; i < 16384; i += 64) {
    int v = mi[i];
    bad = bad || (v != 0 && v != 1);
  }
  unsigned long long any = __ballot(bad);
  if (t == 0) flag[0] = (any != 0ull) ? 1 : 0;  // 1 => byte mask, 0 => int32 mask
}

__device__ __forceinline__ unsigned pack_words(const void* maskp, int mode, int w) {
  unsigned bits = 0;
  if (mode) {
    const uint4* p = (const uint4*)((const unsigned char*)maskp + (size_t)w * 32);
#pragma unroll
    for (int q = 0; q < 2; ++q) {
      uint4 v = p[q];
      unsigned vv[4] = {v.x, v.y, v.z, v.w};
#pragma unroll
      for (int e = 0; e < 4; ++e) {
        unsigned byte4 = vv[e];
#pragma unroll
        for (int bb = 0; bb < 4; ++bb)
          bits |= (unsigned)(((byte4 >> (8 * bb)) & 0xffu) != 0) << (q * 16 + e * 4 + bb);
      }
    }
  } else {
    const uint4* p = (const uint4*)((const int*)maskp + (size_t)w * 32);
#pragma unroll
    for (int q = 0; q < 8; ++q) {
      uint4 v = p[q];
      bits |= (unsigned)(v.x != 0) << (q * 4 + 0);
      bits |= (unsigned)(v.y != 0) << (q * 4 + 1);
      bits |= (unsigned)(v.z != 0) << (q * 4 + 2);
      bits |= (unsigned)(v.w != 0) << (q * 4 + 3);
    }
  }
  return bits;
}

__global__ __launch_bounds__(256) void pack_mask(const void* __restrict__ maskp,
                                                 const int* __restrict__ flag,
                                                 unsigned* __restrict__ pk) {
  int w = blockIdx.x * 256 + threadIdx.x;
  pk[w] = pack_words(maskp, flag[0], w);
}

__device__ __forceinline__ void cvt8(const float* in, us* out, int i) {
  float4 a = ((const float4*)in)[2 * i];
  float4 b = ((const float4*)in)[2 * i + 1];
  us u[8] = {f2h(a.x), f2h(a.y), f2h(a.z), f2h(a.w),
             f2h(b.x), f2h(b.y), f2h(b.z), f2h(b.w)};
  ((uint4*)out)[i] = *(uint4*)u;
}

__global__ __launch_bounds__(256) void cvt_f16x3(const float* __restrict__ i0,
                                                 const float* __restrict__ i1,
                                                 const float* __restrict__ i2,
                                                 us* __restrict__ o0, us* __restrict__ o1,
                                                 us* __restrict__ o2) {
  int z = blockIdx.x >> 12;
  int i = (blockIdx.x & 4095) * 256 + threadIdx.x;
  const float* in = z == 0 ? i0 : z == 1 ? i1 : i2;
  us* out = z == 0 ? o0 : z == 1 ? o1 : o2;
  cvt8(in, out, i);
}

// ---------------- merged prep (fused path): weights + detect ----------------
__global__ __launch_bounds__(256) void prep_w(
    const float* __restrict__ w0, const float* __restrict__ w1,
    const float* __restrict__ w2, const float* __restrict__ w3,
    us* __restrict__ d0, us* __restrict__ d1, us* __restrict__ d2, us* __restrict__ d3,
    const int* __restrict__ mi, int* __restrict__ flag) {
  if (blockIdx.x == 2048) {
    int t = threadIdx.x;
    if (t >= 64) return;
    bool bad = false;
    for (int i = t; i < 16384; i += 64) {
      int v = mi[i];
      bad = bad || (v != 0 && v != 1);
    }
    unsigned long long any = __ballot(bad);
    if (t == 0) flag[0] = (any != 0ull) ? 1 : 0;
    return;
  }
  int which = blockIdx.x >> 9;
  int i = (blockIdx.x & 511) * 256 + threadIdx.x;
  const float* w = which == 0 ? w0 : which == 1 ? w1 : which == 2 ? w2 : w3;
  us* d = which == 0 ? d0 : which == 1 ? d1 : which == 2 ? d2 : d3;
  cvt8(w, d, i);
}

// ---------------- merged prep: mask-pack + q/k/v convert --------------------
__global__ __launch_bounds__(256) void prep_in(
    const void* __restrict__ maskp, const int* __restrict__ flag, unsigned* __restrict__ pk,
    const float* __restrict__ i0, const float* __restrict__ i1, const float* __restrict__ i2,
    us* __restrict__ o0, us* __restrict__ o1, us* __restrict__ o2) {
  if (blockIdx.x < 2048) {
    int w = blockIdx.x * 256 + threadIdx.x;
    pk[w] = pack_words(maskp, flag[0], w);
    return;
  }
  int c = blockIdx.x - 2048;
  int z = c >> 12;
  int i = (c & 4095) * 256 + threadIdx.x;
  const float* in = z == 0 ? i0 : z == 1 ? i1 : i2;
  us* out = z == 0 ? o0 : z == 1 ? o1 : o2;
  cvt8(in, out, i);
}

__device__ __forceinline__ void gload16(const us* g, us* l) {
  __builtin_amdgcn_global_load_lds((const __attribute__((address_space(1))) void*)g,
                                   (__attribute__((address_space(3))) void*)l, 16, 0, 0);
}

// ---------------- 2-phase MFMA GEMM (R9 structure): C = A * W^T + bias ------
// 128x128 tile, BK=64, 4 waves, dbuf LDS (64KB), gload_lds w16, XOR swizzle.
// OMODE 0: fp32 [M][N].  OMODE 2: f16 head-split [b][h][s][64];
//   z == trans_z: epilogue writes V^T layout [bh][d][S] instead.
__device__ __forceinline__ int swzb(int row, int c16) {  // [128][64] f16 tile, XOR swz
  return row * 128 + ((c16 ^ (row & 7)) << 4);
}

template <int OMODE>
__global__ __launch_bounds__(256) void gemm2p(
    const us* __restrict__ A0, const us* __restrict__ A1, const us* __restrict__ A2,
    const us* __restrict__ Wp0, const us* __restrict__ Wp1, const us* __restrict__ Wp2,
    const float* __restrict__ b0, const float* __restrict__ b1, const float* __restrict__ b2,
    void* __restrict__ C0, void* __restrict__ C1, void* __restrict__ C2,
    int M, int N, int K, int trans_z) {
  __shared__ __align__(16) us SM[32768];  // As: bb*8192, Ws: 16384 + bb*8192

  const int z = blockIdx.z;
  const us* A = z == 0 ? A0 : z == 1 ? A1 : A2;
  const us* W = z == 0 ? Wp0 : z == 1 ? Wp1 : Wp2;
  const float* bias = z == 0 ? b0 : z == 1 ? b1 : b2;
  void* Cp = z == 0 ? C0 : z == 1 ? C1 : C2;

  const int m0 = blockIdx.x * 128;
  const int n0 = blockIdx.y * 128;
  const int t = threadIdx.x;
  const int w = t >> 6, l = t & 63;
  const int l15 = l & 15, l4 = l >> 4;
  const int wm = w >> 1, wn = w & 1;

  int goff[4];
#pragma unroll
  for (int j = 0; j < 4; ++j) {
    int u = t + j * 256;
    int r = u >> 3, c8 = u & 7;
    int g = c8 ^ (r & 7);  // XOR involution: linear LDS dest, pre-swizzled src
    goff[j] = r * K + g * 8;
  }
  const us* Ag = A + (size_t)m0 * K;
  const us* Wg = W + (size_t)n0 * K;

  f32x4 acc[4][4];
#pragma unroll
  for (int m = 0; m < 4; ++m)
#pragma unroll
    for (int n = 0; n < 4; ++n) acc[m][n] = (f32x4){0.f, 0.f, 0.f, 0.f};

  auto stage = [&](int k0, int bb) {
#pragma unroll
    for (int j = 0; j < 4; ++j) {
      int u = t + j * 256;
      gload16(Ag + goff[j] + k0, SM + bb * 8192 + u * 8);
      gload16(Wg + goff[j] + k0, SM + 16384 + bb * 8192 + u * 8);
    }
  };

  stage(0, 0);
  __syncthreads();
  int cur = 0;
  for (int k0 = 0; k0 < K; k0 += 64) {
    if (k0 + 64 < K) stage(k0 + 64, cur ^ 1);
#pragma unroll
    for (int ks = 0; ks < 2; ++ks) {
      short8 ah[4], bh_[4];
#pragma unroll
      for (int m = 0; m < 4; ++m)
        ah[m] = *(const short8*)((const char*)(SM + cur * 8192) +
                                 swzb(wm * 64 + m * 16 + l15, ks * 4 + l4));
#pragma unroll
      for (int n = 0; n < 4; ++n)
        bh_[n] = *(const short8*)((const char*)(SM + 16384 + cur * 8192) +
                                  swzb(wn * 64 + n * 16 + l15, ks * 4 + l4));
#pragma unroll
      for (int m = 0; m < 4; ++m)
#pragma unroll
        for (int n = 0; n < 4; ++n)
          acc[m][n] = __builtin_amdgcn_mfma_f32_16x16x32_f16(ah[m], bh_[n], acc[m][n], 0, 0, 0);
    }
    __syncthreads();
    cur ^= 1;
  }

  float bv[4];
#pragma unroll
  for (int n = 0; n < 4; ++n) bv[n] = bias[n0 + wn * 64 + n * 16 + l15];

  if (OMODE == 2 && z == trans_z) {
    // ---- transposed epilogue: write V^T [bh][d][S] via LDS [128 col][136 s] ----
    us* T = SM;
#pragma unroll
    for (int n = 0; n < 4; ++n) {
      int col = wn * 64 + n * 16 + l15;
#pragma unroll
      for (int m = 0; m < 4; ++m) {
        int sr = wm * 64 + m * 16 + l4 * 4;
#pragma unroll
        for (int ip = 0; ip < 2; ++ip) {
          us h0 = f2h(acc[m][n][2 * ip] + bv[n]);
          us h1 = f2h(acc[m][n][2 * ip + 1] + bv[n]);
          *(unsigned*)&T[col * 136 + sr + 2 * ip] = (unsigned)h0 | ((unsigned)h1 << 16);
        }
      }
    }
    __syncthreads();
    const int b = m0 >> 11, sb = m0 & (S_ - 1);
    const int colr = t >> 1, sc = (t & 1) << 6;
    const int hh = (n0 >> 6) + (colr >> 6), d = colr & 63;
    us* dst = (us*)Cp + (((size_t)(b * H_ + hh) << 6) + (size_t)d) * S_ + sb + sc;
#pragma unroll
    for (int p = 0; p < 8; ++p)
      *(uint4*)(dst + p * 8) = *(const uint4*)&T[colr * 136 + sc + p * 8];
    return;
  }

#pragma unroll
  for (int m = 0; m < 4; ++m) {
#pragma unroll
    for (int i = 0; i < 4; ++i) {
      int gm = m0 + wm * 64 + m * 16 + l4 * 4 + i;
#pragma unroll
      for (int n = 0; n < 4; ++n) {
        int gn = n0 + wn * 64 + n * 16 + l15;
        float o = acc[m][n][i] + bv[n];
        if constexpr (OMODE == 0) {
          ((float*)Cp)[(size_t)gm * N + gn] = o;
        } else {
          int b = gm >> 11, s = gm & (S_ - 1);
          int hh = gn >> 6, d = gn & 63;
          size_t idx = (((size_t)(b * H_ + hh) << 11) + s) * 64 + d;
          ((us*)Cp)[idx] = f2h(o);
        }
      }
    }
  }
}

// ---------------- MFMA flash attention (fp16, swapped-S^T, QBLK=256) --------
// 16 waves / 1024 thr; 512 blocks = exactly 2/CU, 32 waves/CU. Waves 0-7
// stage K, 8-15 stage V (1 gload16/thread/tile).
__device__ __forceinline__ int swz(int row, int bc) {  // [64][64] f16 tile, XOR swz
  return (row << 7) + (bc ^ ((row & 7) << 4));
}

__global__ __launch_bounds__(1024) void attn_mfma(
    const us* __restrict__ qh, const us* __restrict__ kh,
    const us* __restrict__ vt, const unsigned* __restrict__ pk,
    us* __restrict__ xout) {
  __shared__ __align__(16) us Ks[2][4096];   // [64 k][64 d] f16, XOR-swizzled
  __shared__ __align__(16) us Vs[2][4096];   // [64 d][64 k]
  __shared__ __align__(16) char Ps[32768];   // [256 q][64 k] f16 (wave-private rows)
  __shared__ __align__(16) float MLutF[64];  // nibble -> f32x4 additive mask

  // XCD swizzle: 512 blocks (bijective remap); 64 bh x 8 q-tiles of 256 rows.
  const int blk = ((blockIdx.x & 7) << 6) + (blockIdx.x >> 3);
  const int bh = blk >> 3;            // 0..63
  const int q0 = (blk & 7) << 8;      // 0..1792
  const int b = bh >> 4, h = bh & (H_ - 1);
  const int t = threadIdx.x;
  const int w = t >> 6, l = t & 63;
  const int l15 = l & 15, l4 = l >> 4;

  short8 qf[2];
  {
    const size_t qbase = ((size_t)bh * S_ + q0 + 16 * w + l15) * 64 + l4 * 8;
    qf[0] = *(const short8*)(qh + qbase);
    qf[1] = *(const short8*)(qh + qbase + 32);
  }

  f32x4 accO[4];
#pragma unroll
  for (int jd = 0; jd < 4; ++jd) accO[jd] = (f32x4){0.f, 0.f, 0.f, 0.f};
  float m_i = -1e30f, l_p = 0.f;  // per-lane: query l15's running max / partial sum

  // staging: 512 chunks/array; threads 0-511 stage K, 512-1023 stage V
  const int sc = t & 511;
  const int r_st = sc >> 3, c_st = (sc & 7) ^ ((sc >> 3) & 7);
  const bool isK = t < 512;
  const us* kh_src = kh + ((size_t)bh * S_ + r_st) * 64 + c_st * 8;
  const us* vt_src = vt + ((size_t)bh * 64 + r_st) * S_ + c_st * 8;

  auto stage = [&](int k0, int bb) {
    if (isK)
      gload16(kh_src + (size_t)k0 * 64, &Ks[bb][sc * 8]);
    else
      gload16(vt_src + k0, &Vs[bb][sc * 8]);
  };

  if (t < 64) MLutF[t] = (((t >> 2) >> (t & 3)) & 1) ? NEGV : 0.f;
  stage(0, 0);
  __syncthreads();
  int cur = 0;

  char* Pw = Ps + w * 2048;     // wave-private 16 rows
  const int prowb = l15 * 128;  // row byte offset
  const int rr7 = l15 & 7;
  const int bhalf = l4 >> 1;
  const int wsub = (l4 & 1) * 8;
  const unsigned* pb = pk + ((size_t)b * S_ + q0 + 16 * w + l15) * (S_ / 32);

  for (int k0 = 0; k0 < S_; k0 += 64) {
    uint2 mw = *(const uint2*)(pb + (k0 >> 5));
    if (k0 + 64 < S_) stage(k0 + 64, cur ^ 1);

    const char* KT = (const char*)Ks[cur];
    const char* VT = (const char*)Vs[cur];

    // ---- S^T = K · Q^T : lane holds S[key = 16j+4*l4+i][q = l15] ----
    __builtin_amdgcn_s_setprio(1);
    f32x4 sj[4];
#pragma unroll
    for (int j = 0; j < 4; ++j) {
      f32x4 s = {0.f, 0.f, 0.f, 0.f};
#pragma unroll
      for (int c = 0; c < 2; ++c) {
        short8 kf = *(const short8*)(KT + swz(l15 + 16 * j, l4 * 16 + 64 * c));
        s = __builtin_amdgcn_mfma_f32_16x16x32_f16(kf, qf[c], s, 0, 0, 0);
      }
      sj[j] = s;
    }
    __builtin_amdgcn_s_setprio(0);

    // ---- mask via f32x4 LDS LUT (nibble-indexed additive {0, NEG}) ----
#pragma unroll
    for (int j = 0; j < 4; ++j) {
      unsigned wrd = (j < 2) ? mw.x : mw.y;
      unsigned nib = (wrd >> (((j & 1) << 4) + (l4 << 2))) & 0xFu;
      f32x4 lv = *(const f32x4*)&MLutF[nib << 2];
      sj[j] = sj[j] + lv;
    }

    // ---- lane-local max (max3-friendly nesting) + 2 shuffles ----
    float c0 = fmaxf(fmaxf(sj[0][0], sj[0][1]), sj[0][2]);
    float c1 = fmaxf(fmaxf(sj[0][3], sj[1][0]), sj[1][1]);
    float c2 = fmaxf(fmaxf(sj[1][2], sj[1][3]), sj[2][0]);
    float c3 = fmaxf(fmaxf(sj[2][1], sj[2][2]), sj[2][3]);
    float c4 = fmaxf(fmaxf(sj[3][0], sj[3][1]), sj[3][2]);
    float tm = fmaxf(fmaxf(fmaxf(c0, c1), c2), fmaxf(fmaxf(c3, c4), sj[3][3]));
    tm = fmaxf(tm, __shfl_xor(tm, 16));
    tm = fmaxf(tm, __shfl_xor(tm, 32));

    // ---- defer-max rescale (rare, wave-uniform) ----
    if (__any(tm - m_i > 8.0f)) {
      float mnew = fmaxf(m_i, tm);
      float scl = exp2a((m_i - mnew) * L2E);
      l_p *= scl;
      m_i = mnew;
      float sr0 = __shfl(scl, 4 * l4 + 0);
      float sr1 = __shfl(scl, 4 * l4 + 1);
      float sr2 = __shfl(scl, 4 * l4 + 2);
      float sr3 = __shfl(scl, 4 * l4 + 3);
#pragma unroll
      for (int jd = 0; jd < 4; ++jd) {
        accO[jd][0] *= sr0; accO[jd][1] *= sr1;
        accO[jd][2] *= sr2; accO[jd][3] *= sr3;
      }
    }

    // ---- exp (exp2-folded, f32) + pack f16 + 4x b64 P writes + pk l-sum ----
    float ml2 = m_i * L2E;
    hf2 acc2;
    acc2.x = (_Float16)0.f;
    acc2.y = (_Float16)0.f;
#pragma unroll
    for (int j = 0; j < 4; ++j) {
      float p0 = exp2a(fmaf(sj[j][0], L2E, -ml2));
      float p1 = exp2a(fmaf(sj[j][1], L2E, -ml2));
      float p2 = exp2a(fmaf(sj[j][2], L2E, -ml2));
      float p3 = exp2a(fmaf(sj[j][3], L2E, -ml2));
      unsigned d0, d1;
      asm("v_cvt_pkrtz_f16_f32 %0, %1, %2" : "=v"(d0) : "v"(p0), "v"(p1));
      asm("v_cvt_pkrtz_f16_f32 %0, %1, %2" : "=v"(d1) : "v"(p2), "v"(p3));
      union { unsigned u; hf2 h; } c0u, c1u;
      c0u.u = d0;
      c1u.u = d1;
      acc2 = acc2 + c0u.h + c1u.h;
      int chunk = ((j << 1) | bhalf) ^ rr7;
      *(u64*)(Pw + prowb + (chunk << 4) + wsub) = (u64)d0 | ((u64)d1 << 32);
    }
    l_p += (float)acc2.x + (float)acc2.y;
    // in-wave ordering: P writes land before A-frag reads
    asm volatile("s_waitcnt lgkmcnt(0)" ::: "memory");
    __builtin_amdgcn_sched_barrier(0);

    // ---- PV ----
    __builtin_amdgcn_s_setprio(1);
#pragma unroll
    for (int kc = 0; kc < 2; ++kc) {
      int chR = (4 * kc + l4) ^ rr7;
      short8 pa = *(const short8*)(Pw + prowb + (chR << 4));
#pragma unroll
      for (int jd = 0; jd < 4; ++jd) {
        short8 vb = *(const short8*)(VT + swz(l15 + 16 * jd, l4 * 16 + 64 * kc));
        accO[jd] = __builtin_amdgcn_mfma_f32_16x16x32_f16(pa, vb, accO[jd], 0, 0, 0);
      }
    }
    __builtin_amdgcn_s_setprio(0);
    __syncthreads();
    cur ^= 1;
  }

  // epilogue: reduce partial l across l4 groups, redistribute to accO rows
  float lr = l_p;
  lr += __shfl_xor(lr, 16);
  lr += __shfl_xor(lr, 32);
  float inv0 = 1.f / __shfl(lr, 4 * l4 + 0);
  float inv1 = 1.f / __shfl(lr, 4 * l4 + 1);
  float inv2 = 1.f / __shfl(lr, 4 * l4 + 2);
  float inv3 = 1.f / __shfl(lr, 4 * l4 + 3);
  float invs[4] = {inv0, inv1, inv2, inv3};
#pragma unroll
  for (int i = 0; i < 4; ++i) {
    int row = q0 + 16 * w + l4 * 4 + i;
    size_t obase = ((size_t)b * S_ + row) * D_ + h * 64 + l15;
#pragma unroll
    for (int jd = 0; jd < 4; ++jd) xout[obase + 16 * jd] = f2h(accO[jd][i] * invs[i]);
  }
}

extern "C" void kernel_launch(void* const* d_in, const int* in_sizes, int n_in,
                              void* d_out, int out_size, void* d_ws, size_t ws_size,
                              hipStream_t stream) {
  const float* q = (const float*)d_in[0];
  const float* k = (const float*)d_in[1];
  const float* v = (const float*)d_in[2];
  const void* mask = d_in[3];
  const float* wq_w = (const float*)d_in[4];
  const float* wq_b = (const float*)d_in[5];
  const float* wk_w = (const float*)d_in[6];
  const float* wk_b = (const float*)d_in[7];
  const float* wv_w = (const float*)d_in[8];
  const float* wv_b = (const float*)d_in[9];
  const float* wo_w = (const float*)d_in[10];
  const float* wo_b = (const float*)d_in[11];

  const size_t NE = (size_t)B_ * S_ * D_;  // 8M elems
  const size_t NW = (size_t)D_ * D_;       // 1M elems
  const size_t PKB = (size_t)(B_ * S_ * (S_ / 32)) * 4;  // 2MB
  char* ws = (char*)d_ws;
  int* flag = (int*)ws;
  unsigned* pkb = (unsigned*)(ws + 256);
  us* base = (us*)(ws + 256 + PKB);

  dim3 g3(64, 8, 3);
  dim3 g2(64, 8, 2);
  dim3 g1(64, 8, 1);

  const size_t fused_need = 256 + PKB + 6 * NE * 2 + 4 * NW * 2;
  if (ws_size >= fused_need) {
    us* A0 = base;          // q f16 -> later xo
    us* A1 = A0 + NE;       // k f16
    us* A2 = A1 + NE;       // v f16
    us* A3 = A2 + NE;       // qh
    us* A4 = A3 + NE;       // kh
    us* A5 = A4 + NE;       // vt
    us* W0 = A5 + NE;
    us* W1 = W0 + NW;
    us* W2 = W1 + NW;
    us* W3 = W2 + NW;
    prep_w<<<2049, 256, 0, stream>>>(wq_w, wk_w, wv_w, wo_w, W0, W1, W2, W3,
                                     (const int*)mask, flag);
    prep_in<<<2048 + 3 * 4096, 256, 0, stream>>>(mask, flag, pkb, q, k, v, A0, A1, A2);
    gemm2p<2><<<g3, 256, 0, stream>>>(A0, A1, A2, W0, W1, W2, wq_b, wk_b, wv_b,
                                      A3, A4, A5, B_ * S_, D_, D_, 2);
    attn_mfma<<<512, 1024, 0, stream>>>(A3, A4, A5, pkb, A0);  // xo in A0
    gemm2p<0><<<g1, 256, 0, stream>>>(A0, A0, A0, W3, W3, W3, wo_b, wo_b, wo_b,
                                      d_out, d_out, d_out, B_ * S_, D_, D_, -1);
  } else {
    // sequential 5-buffer plan
    us* A0 = base;
    us* A1 = A0 + NE;
    us* A2 = A1 + NE;  // qh
    us* A3 = A2 + NE;  // kh
    us* A4 = A3 + NE;  // vt
    us* W0 = A4 + NE;
    us* W1 = W0 + NW;
    us* W2 = W1 + NW;
    us* W3 = W2 + NW;
    detect_mask_kernel<<<1, 64, 0, stream>>>((const int*)mask, flag);
    pack_mask<<<2048, 256, 0, stream>>>(mask, flag, pkb);
    prep_w<<<2048, 256, 0, stream>>>(wq_w, wk_w, wv_w, wo_w, W0, W1, W2, W3,
                                     (const int*)mask, flag);
    cvt_f16x3<<<2 * 4096, 256, 0, stream>>>(q, k, nullptr, A0, A1, nullptr);
    gemm2p<2><<<g2, 256, 0, stream>>>(A0, A1, nullptr, W0, W1, nullptr, wq_b, wk_b, nullptr,
                                      A2, A3, nullptr, B_ * S_, D_, D_, -1);
    cvt_f16x3<<<4096, 256, 0, stream>>>(v, nullptr, nullptr, A0, nullptr, nullptr);
    gemm2p<2><<<g1, 256, 0, stream>>>(A0, nullptr, nullptr, W2, nullptr, nullptr,
                                      wv_b, nullptr, nullptr, A4, nullptr, nullptr,
                                      B_ * S_, D_, D_, 0);  // V -> vt (transposed)
    attn_mfma<<<512, 1024, 0, stream>>>(A2, A3, A4, pkb, A0);  // xo in A0
    gemm2p<0><<<g1, 256, 0, stream>>>(A0, nullptr, nullptr, W3, nullptr, nullptr,
                                      wo_b, nullptr, nullptr, d_out, nullptr, nullptr,
                                      B_ * S_, D_, D_, -1);
  }
}

// Round 14
// 335.996 us; speedup vs baseline: 1.0846x; 1.0383x over previous
//
#include <hip/hip_runtime.h>
#include <hip/hip_bf16.h>

#define B_ 4
#define S_ 2048
#define D_ 1024
#define H_ 16
#define NEGV (-100000.0f)
#define L2E 1.4426950408889634f

typedef __attribute__((ext_vector_type(8))) short short8;
typedef __attribute__((ext_vector_type(4))) float f32x4;
typedef _Float16 hf2 __attribute__((ext_vector_type(2)));
typedef unsigned short us;
typedef unsigned long long u64;

// f32 -> f16 RTNE
__device__ __forceinline__ us f2h(float f) {
  union { _Float16 h; us u; } c;
  c.h = (_Float16)f;
  return c.u;
}
__device__ __forceinline__ float exp2a(float x) {
  float r;
  asm("v_exp_f32 %0, %1" : "=v"(r) : "v"(x));
  return r;
}

// ---------------- standalone prep kernels (fallback path) -------------------
__global__ void detect_mask_kernel(const int* __restrict__ mi, int* __restrict__ flag) {
  int t = threadIdx.x;
  bool bad = false;
  for (int i = t; i < 16384; i += 64) {
    int v = mi[i];
    bad = bad || (v != 0 && v != 1);
  }
  unsigned long long any = __ballot(bad);
  if (t == 0) flag[0] = (any != 0ull) ? 1 : 0;  // 1 => byte mask, 0 => int32 mask
}

__device__ __forceinline__ unsigned pack_words(const void* maskp, int mode, int w) {
  unsigned bits = 0;
  if (mode) {
    const uint4* p = (const uint4*)((const unsigned char*)maskp + (size_t)w * 32);
#pragma unroll
    for (int q = 0; q < 2; ++q) {
      uint4 v = p[q];
      unsigned vv[4] = {v.x, v.y, v.z, v.w};
#pragma unroll
      for (int e = 0; e < 4; ++e) {
        unsigned byte4 = vv[e];
#pragma unroll
        for (int bb = 0; bb < 4; ++bb)
          bits |= (unsigned)(((byte4 >> (8 * bb)) & 0xffu) != 0) << (q * 16 + e * 4 + bb);
      }
    }
  } else {
    const uint4* p = (const uint4*)((const int*)maskp + (size_t)w * 32);
#pragma unroll
    for (int q = 0; q < 8; ++q) {
      uint4 v = p[q];
      bits |= (unsigned)(v.x != 0) << (q * 4 + 0);
      bits |= (unsigned)(v.y != 0) << (q * 4 + 1);
      bits |= (unsigned)(v.z != 0) << (q * 4 + 2);
      bits |= (unsigned)(v.w != 0) << (q * 4 + 3);
    }
  }
  return bits;
}

__global__ __launch_bounds__(256) void pack_mask(const void* __restrict__ maskp,
                                                 const int* __restrict__ flag,
                                                 unsigned* __restrict__ pk) {
  int w = blockIdx.x * 256 + threadIdx.x;
  pk[w] = pack_words(maskp, flag[0], w);
}

__device__ __forceinline__ void cvt8(const float* in, us* out, int i) {
  float4 a = ((const float4*)in)[2 * i];
  float4 b = ((const float4*)in)[2 * i + 1];
  us u[8] = {f2h(a.x), f2h(a.y), f2h(a.z), f2h(a.w),
             f2h(b.x), f2h(b.y), f2h(b.z), f2h(b.w)};
  ((uint4*)out)[i] = *(uint4*)u;
}

__global__ __launch_bounds__(256) void cvt_f16x3(const float* __restrict__ i0,
                                                 const float* __restrict__ i1,
                                                 const float* __restrict__ i2,
                                                 us* __restrict__ o0, us* __restrict__ o1,
                                                 us* __restrict__ o2) {
  int z = blockIdx.x >> 12;
  int i = (blockIdx.x & 4095) * 256 + threadIdx.x;
  const float* in = z == 0 ? i0 : z == 1 ? i1 : i2;
  us* out = z == 0 ? o0 : z == 1 ? o1 : o2;
  cvt8(in, out, i);
}

// ---------------- merged prep (fused path): weights + detect ----------------
__global__ __launch_bounds__(256) void prep_w(
    const float* __restrict__ w0, const float* __restrict__ w1,
    const float* __restrict__ w2, const float* __restrict__ w3,
    us* __restrict__ d0, us* __restrict__ d1, us* __restrict__ d2, us* __restrict__ d3,
    const int* __restrict__ mi, int* __restrict__ flag) {
  if (blockIdx.x == 2048) {
    int t = threadIdx.x;
    if (t >= 64) return;
    bool bad = false;
    for (int i = t; i < 16384; i += 64) {
      int v = mi[i];
      bad = bad || (v != 0 && v != 1);
    }
    unsigned long long any = __ballot(bad);
    if (t == 0) flag[0] = (any != 0ull) ? 1 : 0;
    return;
  }
  int which = blockIdx.x >> 9;
  int i = (blockIdx.x & 511) * 256 + threadIdx.x;
  const float* w = which == 0 ? w0 : which == 1 ? w1 : which == 2 ? w2 : w3;
  us* d = which == 0 ? d0 : which == 1 ? d1 : which == 2 ? d2 : d3;
  cvt8(w, d, i);
}

// ---------------- merged prep: mask-pack + q/k/v convert --------------------
__global__ __launch_bounds__(256) void prep_in(
    const void* __restrict__ maskp, const int* __restrict__ flag, unsigned* __restrict__ pk,
    const float* __restrict__ i0, const float* __restrict__ i1, const float* __restrict__ i2,
    us* __restrict__ o0, us* __restrict__ o1, us* __restrict__ o2) {
  if (blockIdx.x < 2048) {
    int w = blockIdx.x * 256 + threadIdx.x;
    pk[w] = pack_words(maskp, flag[0], w);
    return;
  }
  int c = blockIdx.x - 2048;
  int z = c >> 12;
  int i = (c & 4095) * 256 + threadIdx.x;
  const float* in = z == 0 ? i0 : z == 1 ? i1 : i2;
  us* out = z == 0 ? o0 : z == 1 ? o1 : o2;
  cvt8(in, out, i);
}

__device__ __forceinline__ void gload16(const us* g, us* l) {
  __builtin_amdgcn_global_load_lds((const __attribute__((address_space(1))) void*)g,
                                   (__attribute__((address_space(3))) void*)l, 16, 0, 0);
}

// ---------------- 2-phase MFMA GEMM: C = A * W^T + bias ---------------------
// 128x128 tile, BK=64, 4 waves, dbuf LDS (64KB), gload_lds w16, XOR swizzle.
// OMODE 0: fp32 [M][N].  OMODE 2: f16 head-split [b][h][s][64];
//   z == trans_z: epilogue writes V^T layout [bh][d][S] instead.
__device__ __forceinline__ int swzb(int row, int c16) {  // [128][64] f16 tile, XOR swz
  return row * 128 + ((c16 ^ (row & 7)) << 4);
}

template <int OMODE>
__global__ __launch_bounds__(256) void gemm2p(
    const us* __restrict__ A0, const us* __restrict__ A1, const us* __restrict__ A2,
    const us* __restrict__ Wp0, const us* __restrict__ Wp1, const us* __restrict__ Wp2,
    const float* __restrict__ b0, const float* __restrict__ b1, const float* __restrict__ b2,
    void* __restrict__ C0, void* __restrict__ C1, void* __restrict__ C2,
    int M, int N, int K, int trans_z) {
  __shared__ __align__(16) us SM[32768];  // As: bb*8192, Ws: 16384 + bb*8192

  const int z = blockIdx.z;
  const us* A = z == 0 ? A0 : z == 1 ? A1 : A2;
  const us* W = z == 0 ? Wp0 : z == 1 ? Wp1 : Wp2;
  const float* bias = z == 0 ? b0 : z == 1 ? b1 : b2;
  void* Cp = z == 0 ? C0 : z == 1 ? C1 : C2;

  const int m0 = blockIdx.x * 128;
  const int n0 = blockIdx.y * 128;
  const int t = threadIdx.x;
  const int w = t >> 6, l = t & 63;
  const int l15 = l & 15, l4 = l >> 4;
  const int wm = w >> 1, wn = w & 1;

  int goff[4];
#pragma unroll
  for (int j = 0; j < 4; ++j) {
    int u = t + j * 256;
    int r = u >> 3, c8 = u & 7;
    int g = c8 ^ (r & 7);  // XOR involution: linear LDS dest, pre-swizzled src
    goff[j] = r * K + g * 8;
  }
  const us* Ag = A + (size_t)m0 * K;
  const us* Wg = W + (size_t)n0 * K;

  f32x4 acc[4][4];
#pragma unroll
  for (int m = 0; m < 4; ++m)
#pragma unroll
    for (int n = 0; n < 4; ++n) acc[m][n] = (f32x4){0.f, 0.f, 0.f, 0.f};

  auto stage = [&](int k0, int bb) {
#pragma unroll
    for (int j = 0; j < 4; ++j) {
      int u = t + j * 256;
      gload16(Ag + goff[j] + k0, SM + bb * 8192 + u * 8);
      gload16(Wg + goff[j] + k0, SM + 16384 + bb * 8192 + u * 8);
    }
  };

  stage(0, 0);
  __syncthreads();
  int cur = 0;
  for (int k0 = 0; k0 < K; k0 += 64) {
    if (k0 + 64 < K) stage(k0 + 64, cur ^ 1);
#pragma unroll
    for (int ks = 0; ks < 2; ++ks) {
      short8 ah[4], bh_[4];
#pragma unroll
      for (int m = 0; m < 4; ++m)
        ah[m] = *(const short8*)((const char*)(SM + cur * 8192) +
                                 swzb(wm * 64 + m * 16 + l15, ks * 4 + l4));
#pragma unroll
      for (int n = 0; n < 4; ++n)
        bh_[n] = *(const short8*)((const char*)(SM + 16384 + cur * 8192) +
                                  swzb(wn * 64 + n * 16 + l15, ks * 4 + l4));
#pragma unroll
      for (int m = 0; m < 4; ++m)
#pragma unroll
        for (int n = 0; n < 4; ++n)
          acc[m][n] = __builtin_amdgcn_mfma_f32_16x16x32_f16(ah[m], bh_[n], acc[m][n], 0, 0, 0);
    }
    __syncthreads();
    cur ^= 1;
  }

  float bv[4];
#pragma unroll
  for (int n = 0; n < 4; ++n) bv[n] = bias[n0 + wn * 64 + n * 16 + l15];

  if (OMODE == 2 && z == trans_z) {
    // ---- transposed epilogue: write V^T [bh][d][S] via LDS [128 col][136 s] ----
    us* T = SM;
#pragma unroll
    for (int n = 0; n < 4; ++n) {
      int col = wn * 64 + n * 16 + l15;
#pragma unroll
      for (int m = 0; m < 4; ++m) {
        int sr = wm * 64 + m * 16 + l4 * 4;
#pragma unroll
        for (int ip = 0; ip < 2; ++ip) {
          us h0 = f2h(acc[m][n][2 * ip] + bv[n]);
          us h1 = f2h(acc[m][n][2 * ip + 1] + bv[n]);
          *(unsigned*)&T[col * 136 + sr + 2 * ip] = (unsigned)h0 | ((unsigned)h1 << 16);
        }
      }
    }
    __syncthreads();
    const int b = m0 >> 11, sb = m0 & (S_ - 1);
    const int colr = t >> 1, sc = (t & 1) << 6;
    const int hh = (n0 >> 6) + (colr >> 6), d = colr & 63;
    us* dst = (us*)Cp + (((size_t)(b * H_ + hh) << 6) + (size_t)d) * S_ + sb + sc;
#pragma unroll
    for (int p = 0; p < 8; ++p)
      *(uint4*)(dst + p * 8) = *(const uint4*)&T[colr * 136 + sc + p * 8];
    return;
  }

#pragma unroll
  for (int m = 0; m < 4; ++m) {
#pragma unroll
    for (int i = 0; i < 4; ++i) {
      int gm = m0 + wm * 64 + m * 16 + l4 * 4 + i;
#pragma unroll
      for (int n = 0; n < 4; ++n) {
        int gn = n0 + wn * 64 + n * 16 + l15;
        float o = acc[m][n][i] + bv[n];
        if constexpr (OMODE == 0) {
          ((float*)Cp)[(size_t)gm * N + gn] = o;
        } else {
          int b = gm >> 11, s = gm & (S_ - 1);
          int hh = gn >> 6, d = gn & 63;
          size_t idx = (((size_t)(b * H_ + hh) << 11) + s) * 64 + d;
          ((us*)Cp)[idx] = f2h(o);
        }
      }
    }
  }
}

// ---------------- MFMA flash attention (fp16, swapped-S^T, QBLK=128) --------
__device__ __forceinline__ int swz(int row, int bc) {  // [64][64] f16 tile, XOR swz
  return (row << 7) + (bc ^ ((row & 7) << 4));
}

__global__ __launch_bounds__(512) void attn_mfma(
    const us* __restrict__ qh, const us* __restrict__ kh,
    const us* __restrict__ vt, const unsigned* __restrict__ pk,
    us* __restrict__ xout) {
  __shared__ __align__(16) us Ks[2][4096];  // [64 k][64 d] f16, XOR-swizzled
  __shared__ __align__(16) us Vs[2][4096];  // [64 d][64 k]
  __shared__ __align__(16) char Ps[16384];  // [128 q][64 k] f16 (wave-private rows)
  __shared__ __align__(16) float MLutF[64]; // nibble -> f32x4 additive mask

  const int blk = ((blockIdx.x & 7) << 7) + (blockIdx.x >> 3);  // XCD swizzle
  const int bh = blk >> 4;
  const int q0 = (blk & 15) << 7;
  const int b = bh >> 4, h = bh & (H_ - 1);
  const int t = threadIdx.x;
  const int w = t >> 6, l = t & 63;
  const int l15 = l & 15, l4 = l >> 4;

  short8 qf[2];
  {
    const size_t qbase = ((size_t)bh * S_ + q0 + 16 * w + l15) * 64 + l4 * 8;
    qf[0] = *(const short8*)(qh + qbase);
    qf[1] = *(const short8*)(qh + qbase + 32);
  }

  f32x4 accO[4];
#pragma unroll
  for (int jd = 0; jd < 4; ++jd) accO[jd] = (f32x4){0.f, 0.f, 0.f, 0.f};
  float m_i = -1e30f, l_p = 0.f;  // per-lane: query l15's running max / partial sum

  const int r_st = t >> 3, c_st = (t & 7) ^ ((t >> 3) & 7);
  const us* kh_src = kh + ((size_t)bh * S_ + r_st) * 64 + c_st * 8;
  const us* vt_src = vt + ((size_t)bh * 64 + r_st) * S_ + c_st * 8;

  auto stage = [&](int k0, int bb) {
    gload16(kh_src + (size_t)k0 * 64, &Ks[bb][t * 8]);
    gload16(vt_src + k0, &Vs[bb][t * 8]);
  };

  if (t < 64) MLutF[t] = (((t >> 2) >> (t & 3)) & 1) ? NEGV : 0.f;
  stage(0, 0);
  __syncthreads();
  int cur = 0;

  char* Pw = Ps + w * 2048;     // wave-private 16 rows
  const int prowb = l15 * 128;  // row byte offset
  const int rr7 = l15 & 7;
  const int bhalf = l4 >> 1;
  const int wsub = (l4 & 1) * 8;
  const unsigned* pb = pk + ((size_t)b * S_ + q0 + 16 * w + l15) * (S_ / 32);

  for (int k0 = 0; k0 < S_; k0 += 64) {
    uint2 mw = *(const uint2*)(pb + (k0 >> 5));
    if (k0 + 64 < S_) stage(k0 + 64, cur ^ 1);

    const char* KT = (const char*)Ks[cur];
    const char* VT = (const char*)Vs[cur];

    // ---- S^T = K · Q^T : lane holds S[key = 16j+4*l4+i][q = l15] ----
    __builtin_amdgcn_s_setprio(1);
    f32x4 sj[4];
#pragma unroll
    for (int j = 0; j < 4; ++j) {
      f32x4 s = {0.f, 0.f, 0.f, 0.f};
#pragma unroll
      for (int c = 0; c < 2; ++c) {
        short8 kf = *(const short8*)(KT + swz(l15 + 16 * j, l4 * 16 + 64 * c));
        s = __builtin_amdgcn_mfma_f32_16x16x32_f16(kf, qf[c], s, 0, 0, 0);
      }
      sj[j] = s;
    }
    __builtin_amdgcn_s_setprio(0);

    // ---- mask via f32x4 LDS LUT (nibble-indexed additive {0, NEG}) ----
#pragma unroll
    for (int j = 0; j < 4; ++j) {
      unsigned wrd = (j < 2) ? mw.x : mw.y;
      unsigned nib = (wrd >> (((j & 1) << 4) + (l4 << 2))) & 0xFu;
      f32x4 lv = *(const f32x4*)&MLutF[nib << 2];
      sj[j] = sj[j] + lv;
    }

    // ---- lane-local max (max3-friendly nesting); cross-lane only if rescale ----
    float c0 = fmaxf(fmaxf(sj[0][0], sj[0][1]), sj[0][2]);
    float c1 = fmaxf(fmaxf(sj[0][3], sj[1][0]), sj[1][1]);
    float c2 = fmaxf(fmaxf(sj[1][2], sj[1][3]), sj[2][0]);
    float c3 = fmaxf(fmaxf(sj[2][1], sj[2][2]), sj[2][3]);
    float c4 = fmaxf(fmaxf(sj[3][0], sj[3][1]), sj[3][2]);
    float tm = fmaxf(fmaxf(fmaxf(c0, c1), c2), fmaxf(fmaxf(c3, c4), sj[3][3]));

    // defer-max: common path needs NO cross-lane reduce (invariant: all lanes'
    // S <= m_i + 8 => P <= 2^11.5, f16-tree-safe). Reduce only when rescaling.
    if (__any(tm - m_i > 8.0f)) {
      float tr = fmaxf(tm, __shfl_xor(tm, 16));
      tr = fmaxf(tr, __shfl_xor(tr, 32));
      float mnew = fmaxf(m_i, tr);
      float scl = exp2a((m_i - mnew) * L2E);
      l_p *= scl;
      m_i = mnew;
      float sr0 = __shfl(scl, 4 * l4 + 0);
      float sr1 = __shfl(scl, 4 * l4 + 1);
      float sr2 = __shfl(scl, 4 * l4 + 2);
      float sr3 = __shfl(scl, 4 * l4 + 3);
#pragma unroll
      for (int jd = 0; jd < 4; ++jd) {
        accO[jd][0] *= sr0; accO[jd][1] *= sr1;
        accO[jd][2] *= sr2; accO[jd][3] *= sr3;
      }
    }

    // ---- exp (exp2-folded, f32) + pack f16 + 4x b64 P writes + pk l-sum ----
    float ml2 = m_i * L2E;
    hf2 acc2;
    acc2.x = (_Float16)0.f;
    acc2.y = (_Float16)0.f;
#pragma unroll
    for (int j = 0; j < 4; ++j) {
      float p0 = exp2a(fmaf(sj[j][0], L2E, -ml2));
      float p1 = exp2a(fmaf(sj[j][1], L2E, -ml2));
      float p2 = exp2a(fmaf(sj[j][2], L2E, -ml2));
      float p3 = exp2a(fmaf(sj[j][3], L2E, -ml2));
      unsigned d0, d1;
      asm("v_cvt_pkrtz_f16_f32 %0, %1, %2" : "=v"(d0) : "v"(p0), "v"(p1));
      asm("v_cvt_pkrtz_f16_f32 %0, %1, %2" : "=v"(d1) : "v"(p2), "v"(p3));
      union { unsigned u; hf2 h; } c0u, c1u;
      c0u.u = d0;
      c1u.u = d1;
      acc2 = acc2 + c0u.h + c1u.h;
      int chunk = ((j << 1) | bhalf) ^ rr7;
      *(u64*)(Pw + prowb + (chunk << 4) + wsub) = (u64)d0 | ((u64)d1 << 32);
    }
    l_p += (float)acc2.x + (float)acc2.y;
    // in-wave ordering: P writes land before A-frag reads
    asm volatile("s_waitcnt lgkmcnt(0)" ::: "memory");
    __builtin_amdgcn_sched_barrier(0);

    // ---- PV ----
    __builtin_amdgcn_s_setprio(1);
#pragma unroll
    for (int kc = 0; kc < 2; ++kc) {
      int chR = (4 * kc + l4) ^ rr7;
      short8 pa = *(const short8*)(Pw + prowb + (chR << 4));
#pragma unroll
      for (int jd = 0; jd < 4; ++jd) {
        short8 vb = *(const short8*)(VT + swz(l15 + 16 * jd, l4 * 16 + 64 * kc));
        accO[jd] = __builtin_amdgcn_mfma_f32_16x16x32_f16(pa, vb, accO[jd], 0, 0, 0);
      }
    }
    __builtin_amdgcn_s_setprio(0);
    __syncthreads();
    cur ^= 1;
  }

  // epilogue: reduce partial l across l4 groups, redistribute to accO rows
  float lr = l_p;
  lr += __shfl_xor(lr, 16);
  lr += __shfl_xor(lr, 32);
  float inv0 = 1.f / __shfl(lr, 4 * l4 + 0);
  float inv1 = 1.f / __shfl(lr, 4 * l4 + 1);
  float inv2 = 1.f / __shfl(lr, 4 * l4 + 2);
  float inv3 = 1.f / __shfl(lr, 4 * l4 + 3);
  float invs[4] = {inv0, inv1, inv2, inv3};
#pragma unroll
  for (int i = 0; i < 4; ++i) {
    int row = q0 + 16 * w + l4 * 4 + i;
    size_t obase = ((size_t)b * S_ + row) * D_ + h * 64 + l15;
#pragma unroll
    for (int jd = 0; jd < 4; ++jd) xout[obase + 16 * jd] = f2h(accO[jd][i] * invs[i]);
  }
}

extern "C" void kernel_launch(void* const* d_in, const int* in_sizes, int n_in,
                              void* d_out, int out_size, void* d_ws, size_t ws_size,
                              hipStream_t stream) {
  const float* q = (const float*)d_in[0];
  const float* k = (const float*)d_in[1];
  const float* v = (const float*)d_in[2];
  const void* mask = d_in[3];
  const float* wq_w = (const float*)d_in[4];
  const float* wq_b = (const float*)d_in[5];
  const float* wk_w = (const float*)d_in[6];
  const float* wk_b = (const float*)d_in[7];
  const float* wv_w = (const float*)d_in[8];
  const float* wv_b = (const float*)d_in[9];
  const float* wo_w = (const float*)d_in[10];
  const float* wo_b = (const float*)d_in[11];

  const size_t NE = (size_t)B_ * S_ * D_;  // 8M elems
  const size_t NW = (size_t)D_ * D_;       // 1M elems
  const size_t PKB = (size_t)(B_ * S_ * (S_ / 32)) * 4;  // 2MB
  char* ws = (char*)d_ws;
  int* flag = (int*)ws;
  unsigned* pkb = (unsigned*)(ws + 256);
  us* base = (us*)(ws + 256 + PKB);

  dim3 g3(64, 8, 3);
  dim3 g2(64, 8, 2);
  dim3 g1(64, 8, 1);

  const size_t fused_need = 256 + PKB + 6 * NE * 2 + 4 * NW * 2;
  if (ws_size >= fused_need) {
    us* A0 = base;          // q f16 -> later xo
    us* A1 = A0 + NE;       // k f16
    us* A2 = A1 + NE;       // v f16
    us* A3 = A2 + NE;       // qh
    us* A4 = A3 + NE;       // kh
    us* A5 = A4 + NE;       // vt
    us* W0 = A5 + NE;
    us* W1 = W0 + NW;
    us* W2 = W1 + NW;
    us* W3 = W2 + NW;
    prep_w<<<2049, 256, 0, stream>>>(wq_w, wk_w, wv_w, wo_w, W0, W1, W2, W3,
                                     (const int*)mask, flag);
    prep_in<<<2048 + 3 * 4096, 256, 0, stream>>>(mask, flag, pkb, q, k, v, A0, A1, A2);
    gemm2p<2><<<g3, 256, 0, stream>>>(A0, A1, A2, W0, W1, W2, wq_b, wk_b, wv_b,
                                      A3, A4, A5, B_ * S_, D_, D_, 2);
    attn_mfma<<<1024, 512, 0, stream>>>(A3, A4, A5, pkb, A0);  // xo in A0
    gemm2p<0><<<g1, 256, 0, stream>>>(A0, A0, A0, W3, W3, W3, wo_b, wo_b, wo_b,
                                      d_out, d_out, d_out, B_ * S_, D_, D_, -1);
  } else {
    // sequential 5-buffer plan
    us* A0 = base;
    us* A1 = A0 + NE;
    us* A2 = A1 + NE;  // qh
    us* A3 = A2 + NE;  // kh
    us* A4 = A3 + NE;  // vt
    us* W0 = A4 + NE;
    us* W1 = W0 + NW;
    us* W2 = W1 + NW;
    us* W3 = W2 + NW;
    detect_mask_kernel<<<1, 64, 0, stream>>>((const int*)mask, flag);
    pack_mask<<<2048, 256, 0, stream>>>(mask, flag, pkb);
    prep_w<<<2048, 256, 0, stream>>>(wq_w, wk_w, wv_w, wo_w, W0, W1, W2, W3,
                                     (const int*)mask, flag);
    cvt_f16x3<<<2 * 4096, 256, 0, stream>>>(q, k, nullptr, A0, A1, nullptr);
    gemm2p<2><<<g2, 256, 0, stream>>>(A0, A1, nullptr, W0, W1, nullptr, wq_b, wk_b, nullptr,
                                      A2, A3, nullptr, B_ * S_, D_, D_, -1);
    cvt_f16x3<<<4096, 256, 0, stream>>>(v, nullptr, nullptr, A0, nullptr, nullptr);
    gemm2p<2><<<g1, 256, 0, stream>>>(A0, nullptr, nullptr, W2, nullptr, nullptr,
                                      wv_b, nullptr, nullptr, A4, nullptr, nullptr,
                                      B_ * S_, D_, D_, 0);  // V -> vt (transposed)
    attn_mfma<<<1024, 512, 0, stream>>>(A2, A3, A4, pkb, A0);  // xo in A0
    gemm2p<0><<<g1, 256, 0, stream>>>(A0, nullptr, nullptr, W3, nullptr, nullptr,
                                      wo_b, nullptr, nullptr, d_out, nullptr, nullptr,
                                      B_ * S_, D_, D_, -1);
  }
}

// Round 15
// 334.390 us; speedup vs baseline: 1.0898x; 1.0048x over previous
//
#include <hip/hip_runtime.h>
#include <hip/hip_bf16.h>

#define B_ 4
#define S_ 2048
#define D_ 1024
#define H_ 16
#define NEGV (-100000.0f)
#define L2E 1.4426950408889634f

typedef __attribute__((ext_vector_type(8))) short short8;
typedef __attribute__((ext_vector_type(4))) float f32x4;
typedef _Float16 hf2 __attribute__((ext_vector_type(2)));
typedef unsigned short us;
typedef unsigned long long u64;

// f32 -> f16 RTNE
__device__ __forceinline__ us f2h(float f) {
  union { _Float16 h; us u; } c;
  c.h = (_Float16)f;
  return c.u;
}
__device__ __forceinline__ float exp2a(float x) {
  float r;
  asm("v_exp_f32 %0, %1" : "=v"(r) : "v"(x));
  return r;
}

// ---------------- standalone prep kernels (fallback path) -------------------
__global__ void detect_mask_kernel(const int* __restrict__ mi, int* __restrict__ flag) {
  int t = threadIdx.x;
  bool bad = false;
  for (int i = t; i < 16384; i += 64) {
    int v = mi[i];
    bad = bad || (v != 0 && v != 1);
  }
  unsigned long long any = __ballot(bad);
  if (t == 0) flag[0] = (any != 0ull) ? 1 : 0;  // 1 => byte mask, 0 => int32 mask
}

__device__ __forceinline__ unsigned pack_words(const void* maskp, int mode, int w) {
  unsigned bits = 0;
  if (mode) {
    const uint4* p = (const uint4*)((const unsigned char*)maskp + (size_t)w * 32);
#pragma unroll
    for (int q = 0; q < 2; ++q) {
      uint4 v = p[q];
      unsigned vv[4] = {v.x, v.y, v.z, v.w};
#pragma unroll
      for (int e = 0; e < 4; ++e) {
        unsigned byte4 = vv[e];
#pragma unroll
        for (int bb = 0; bb < 4; ++bb)
          bits |= (unsigned)(((byte4 >> (8 * bb)) & 0xffu) != 0) << (q * 16 + e * 4 + bb);
      }
    }
  } else {
    const uint4* p = (const uint4*)((const int*)maskp + (size_t)w * 32);
#pragma unroll
    for (int q = 0; q < 8; ++q) {
      uint4 v = p[q];
      bits |= (unsigned)(v.x != 0) << (q * 4 + 0);
      bits |= (unsigned)(v.y != 0) << (q * 4 + 1);
      bits |= (unsigned)(v.z != 0) << (q * 4 + 2);
      bits |= (unsigned)(v.w != 0) << (q * 4 + 3);
    }
  }
  return bits;
}

__global__ __launch_bounds__(256) void pack_mask(const void* __restrict__ maskp,
                                                 const int* __restrict__ flag,
                                                 unsigned* __restrict__ pk) {
  int w = blockIdx.x * 256 + threadIdx.x;
  pk[w] = pack_words(maskp, flag[0], w);
}

__device__ __forceinline__ void cvt8(const float* in, us* out, int i) {
  float4 a = ((const float4*)in)[2 * i];
  float4 b = ((const float4*)in)[2 * i + 1];
  us u[8] = {f2h(a.x), f2h(a.y), f2h(a.z), f2h(a.w),
             f2h(b.x), f2h(b.y), f2h(b.z), f2h(b.w)};
  ((uint4*)out)[i] = *(uint4*)u;
}

__global__ __launch_bounds__(256) void cvt_f16x3(const float* __restrict__ i0,
                                                 const float* __restrict__ i1,
                                                 const float* __restrict__ i2,
                                                 us* __restrict__ o0, us* __restrict__ o1,
                                                 us* __restrict__ o2) {
  int z = blockIdx.x >> 12;
  int i = (blockIdx.x & 4095) * 256 + threadIdx.x;
  const float* in = z == 0 ? i0 : z == 1 ? i1 : i2;
  us* out = z == 0 ? o0 : z == 1 ? o1 : o2;
  cvt8(in, out, i);
}

// ---------------- merged prep (fused path): weights + detect ----------------
__global__ __launch_bounds__(256) void prep_w(
    const float* __restrict__ w0, const float* __restrict__ w1,
    const float* __restrict__ w2, const float* __restrict__ w3,
    us* __restrict__ d0, us* __restrict__ d1, us* __restrict__ d2, us* __restrict__ d3,
    const int* __restrict__ mi, int* __restrict__ flag) {
  if (blockIdx.x == 2048) {
    int t = threadIdx.x;
    if (t >= 64) return;
    bool bad = false;
    for (int i = t; i < 16384; i += 64) {
      int v = mi[i];
      bad = bad || (v != 0 && v != 1);
    }
    unsigned long long any = __ballot(bad);
    if (t == 0) flag[0] = (any != 0ull) ? 1 : 0;
    return;
  }
  int which = blockIdx.x >> 9;
  int i = (blockIdx.x & 511) * 256 + threadIdx.x;
  const float* w = which == 0 ? w0 : which == 1 ? w1 : which == 2 ? w2 : w3;
  us* d = which == 0 ? d0 : which == 1 ? d1 : which == 2 ? d2 : d3;
  cvt8(w, d, i);
}

// ---------------- merged prep: mask-pack + q/k/v convert --------------------
__global__ __launch_bounds__(256) void prep_in(
    const void* __restrict__ maskp, const int* __restrict__ flag, unsigned* __restrict__ pk,
    const float* __restrict__ i0, const float* __restrict__ i1, const float* __restrict__ i2,
    us* __restrict__ o0, us* __restrict__ o1, us* __restrict__ o2) {
  if (blockIdx.x < 2048) {
    int w = blockIdx.x * 256 + threadIdx.x;
    pk[w] = pack_words(maskp, flag[0], w);
    return;
  }
  int c = blockIdx.x - 2048;
  int z = c >> 12;
  int i = (c & 4095) * 256 + threadIdx.x;
  const float* in = z == 0 ? i0 : z == 1 ? i1 : i2;
  us* out = z == 0 ? o0 : z == 1 ? o1 : o2;
  cvt8(in, out, i);
}

__device__ __forceinline__ void gload16(const us* g, us* l) {
  __builtin_amdgcn_global_load_lds((const __attribute__((address_space(1))) void*)g,
                                   (__attribute__((address_space(3))) void*)l, 16, 0, 0);
}

// ---------------- 2-phase MFMA GEMM: C = A * W^T + bias ---------------------
// 128x128 tile, BK=64, 4 waves, dbuf LDS (64KB), gload_lds w16, XOR swizzle.
// OMODE 0: fp32 [M][N].  OMODE 2: f16 head-split [b][h][s][64];
//   z == trans_z: epilogue writes V^T layout [bh][d][S] instead.
__device__ __forceinline__ int swzb(int row, int c16) {  // [128][64] f16 tile, XOR swz
  return row * 128 + ((c16 ^ (row & 7)) << 4);
}

template <int OMODE>
__global__ __launch_bounds__(256) void gemm2p(
    const us* __restrict__ A0, const us* __restrict__ A1, const us* __restrict__ A2,
    const us* __restrict__ Wp0, const us* __restrict__ Wp1, const us* __restrict__ Wp2,
    const float* __restrict__ b0, const float* __restrict__ b1, const float* __restrict__ b2,
    void* __restrict__ C0, void* __restrict__ C1, void* __restrict__ C2,
    int M, int N, int K, int trans_z) {
  __shared__ __align__(16) us SM[32768];  // As: bb*8192, Ws: 16384 + bb*8192

  const int z = blockIdx.z;
  const us* A = z == 0 ? A0 : z == 1 ? A1 : A2;
  const us* W = z == 0 ? Wp0 : z == 1 ? Wp1 : Wp2;
  const float* bias = z == 0 ? b0 : z == 1 ? b1 : b2;
  void* Cp = z == 0 ? C0 : z == 1 ? C1 : C2;

  const int m0 = blockIdx.x * 128;
  const int n0 = blockIdx.y * 128;
  const int t = threadIdx.x;
  const int w = t >> 6, l = t & 63;
  const int l15 = l & 15, l4 = l >> 4;
  const int wm = w >> 1, wn = w & 1;

  int goff[4];
#pragma unroll
  for (int j = 0; j < 4; ++j) {
    int u = t + j * 256;
    int r = u >> 3, c8 = u & 7;
    int g = c8 ^ (r & 7);  // XOR involution: linear LDS dest, pre-swizzled src
    goff[j] = r * K + g * 8;
  }
  const us* Ag = A + (size_t)m0 * K;
  const us* Wg = W + (size_t)n0 * K;

  f32x4 acc[4][4];
#pragma unroll
  for (int m = 0; m < 4; ++m)
#pragma unroll
    for (int n = 0; n < 4; ++n) acc[m][n] = (f32x4){0.f, 0.f, 0.f, 0.f};

  auto stage = [&](int k0, int bb) {
#pragma unroll
    for (int j = 0; j < 4; ++j) {
      int u = t + j * 256;
      gload16(Ag + goff[j] + k0, SM + bb * 8192 + u * 8);
      gload16(Wg + goff[j] + k0, SM + 16384 + bb * 8192 + u * 8);
    }
  };

  stage(0, 0);
  __syncthreads();
  int cur = 0;
  for (int k0 = 0; k0 < K; k0 += 64) {
    if (k0 + 64 < K) stage(k0 + 64, cur ^ 1);
#pragma unroll
    for (int ks = 0; ks < 2; ++ks) {
      short8 ah[4], bh_[4];
#pragma unroll
      for (int m = 0; m < 4; ++m)
        ah[m] = *(const short8*)((const char*)(SM + cur * 8192) +
                                 swzb(wm * 64 + m * 16 + l15, ks * 4 + l4));
#pragma unroll
      for (int n = 0; n < 4; ++n)
        bh_[n] = *(const short8*)((const char*)(SM + 16384 + cur * 8192) +
                                  swzb(wn * 64 + n * 16 + l15, ks * 4 + l4));
#pragma unroll
      for (int m = 0; m < 4; ++m)
#pragma unroll
        for (int n = 0; n < 4; ++n)
          acc[m][n] = __builtin_amdgcn_mfma_f32_16x16x32_f16(ah[m], bh_[n], acc[m][n], 0, 0, 0);
    }
    __syncthreads();
    cur ^= 1;
  }

  float bv[4];
#pragma unroll
  for (int n = 0; n < 4; ++n) bv[n] = bias[n0 + wn * 64 + n * 16 + l15];

  if (OMODE == 2 && z == trans_z) {
    // ---- transposed epilogue: write V^T [bh][d][S] via LDS [128 col][136 s] ----
    us* T = SM;
#pragma unroll
    for (int n = 0; n < 4; ++n) {
      int col = wn * 64 + n * 16 + l15;
#pragma unroll
      for (int m = 0; m < 4; ++m) {
        int sr = wm * 64 + m * 16 + l4 * 4;
#pragma unroll
        for (int ip = 0; ip < 2; ++ip) {
          us h0 = f2h(acc[m][n][2 * ip] + bv[n]);
          us h1 = f2h(acc[m][n][2 * ip + 1] + bv[n]);
          *(unsigned*)&T[col * 136 + sr + 2 * ip] = (unsigned)h0 | ((unsigned)h1 << 16);
        }
      }
    }
    __syncthreads();
    const int b = m0 >> 11, sb = m0 & (S_ - 1);
    const int colr = t >> 1, sc = (t & 1) << 6;
    const int hh = (n0 >> 6) + (colr >> 6), d = colr & 63;
    us* dst = (us*)Cp + (((size_t)(b * H_ + hh) << 6) + (size_t)d) * S_ + sb + sc;
#pragma unroll
    for (int p = 0; p < 8; ++p)
      *(uint4*)(dst + p * 8) = *(const uint4*)&T[colr * 136 + sc + p * 8];
    return;
  }

#pragma unroll
  for (int m = 0; m < 4; ++m) {
#pragma unroll
    for (int i = 0; i < 4; ++i) {
      int gm = m0 + wm * 64 + m * 16 + l4 * 4 + i;
#pragma unroll
      for (int n = 0; n < 4; ++n) {
        int gn = n0 + wn * 64 + n * 16 + l15;
        float o = acc[m][n][i] + bv[n];
        if constexpr (OMODE == 0) {
          ((float*)Cp)[(size_t)gm * N + gn] = o;
        } else {
          int b = gm >> 11, s = gm & (S_ - 1);
          int hh = gn >> 6, d = gn & 63;
          size_t idx = (((size_t)(b * H_ + hh) << 11) + s) * 64 + d;
          ((us*)Cp)[idx] = f2h(o);
        }
      }
    }
  }
}

// ---------------- MFMA flash attention (fp16, swapped-S^T, QBLK=128) --------
__device__ __forceinline__ int swz(int row, int bc) {  // [64][64] f16 tile, XOR swz
  return (row << 7) + (bc ^ ((row & 7) << 4));
}

__global__ __launch_bounds__(512) void attn_mfma(
    const us* __restrict__ qh, const us* __restrict__ kh,
    const us* __restrict__ vt, const unsigned* __restrict__ pk,
    us* __restrict__ xout) {
  __shared__ __align__(16) us Ks[2][4096];  // [64 k][64 d] f16, XOR-swizzled
  __shared__ __align__(16) us Vs[2][4096];  // [64 d][64 k]
  __shared__ __align__(16) char Ps[16384];  // [128 q][64 k] f16 (wave-private rows)
  __shared__ __align__(16) float MLutF[64]; // nibble -> f32x4 additive mask

  const int blk = ((blockIdx.x & 7) << 7) + (blockIdx.x >> 3);  // XCD swizzle
  const int bh = blk >> 4;
  const int q0 = (blk & 15) << 7;
  const int b = bh >> 4, h = bh & (H_ - 1);
  const int t = threadIdx.x;
  const int w = t >> 6, l = t & 63;
  const int l15 = l & 15, l4 = l >> 4;

  short8 qf[2];
  {
    const size_t qbase = ((size_t)bh * S_ + q0 + 16 * w + l15) * 64 + l4 * 8;
    qf[0] = *(const short8*)(qh + qbase);
    qf[1] = *(const short8*)(qh + qbase + 32);
  }

  f32x4 accO[4];
#pragma unroll
  for (int jd = 0; jd < 4; ++jd) accO[jd] = (f32x4){0.f, 0.f, 0.f, 0.f};
  float m_i = -1e30f, l_p = 0.f;  // per-lane: query l15's running max / partial sum

  const int r_st = t >> 3, c_st = (t & 7) ^ ((t >> 3) & 7);
  const us* kh_src = kh + ((size_t)bh * S_ + r_st) * 64 + c_st * 8;
  const us* vt_src = vt + ((size_t)bh * 64 + r_st) * S_ + c_st * 8;

  auto stage = [&](int k0, int bb) {
    gload16(kh_src + (size_t)k0 * 64, &Ks[bb][t * 8]);
    gload16(vt_src + k0, &Vs[bb][t * 8]);
  };

  if (t < 64) MLutF[t] = (((t >> 2) >> (t & 3)) & 1) ? NEGV : 0.f;
  stage(0, 0);
  __syncthreads();
  int cur = 0;

  char* Pw = Ps + w * 2048;     // wave-private 16 rows
  const int prowb = l15 * 128;  // row byte offset
  const int rr7 = l15 & 7;
  const int bhalf = l4 >> 1;
  const int wsub = (l4 & 1) * 8;
  const unsigned* pb = pk + ((size_t)b * S_ + q0 + 16 * w + l15) * (S_ / 32);

  for (int k0 = 0; k0 < S_; k0 += 64) {
    uint2 mw = *(const uint2*)(pb + (k0 >> 5));
    if (k0 + 64 < S_) stage(k0 + 64, cur ^ 1);

    const char* KT = (const char*)Ks[cur];
    const char* VT = (const char*)Vs[cur];

    // ---- S^T = K · Q^T : lane holds S[key = 16j+4*l4+i][q = l15] ----
    __builtin_amdgcn_s_setprio(1);
    f32x4 sj[4];
#pragma unroll
    for (int j = 0; j < 4; ++j) {
      f32x4 s = {0.f, 0.f, 0.f, 0.f};
#pragma unroll
      for (int c = 0; c < 2; ++c) {
        short8 kf = *(const short8*)(KT + swz(l15 + 16 * j, l4 * 16 + 64 * c));
        s = __builtin_amdgcn_mfma_f32_16x16x32_f16(kf, qf[c], s, 0, 0, 0);
      }
      sj[j] = s;
    }
    __builtin_amdgcn_s_setprio(0);

    // ---- mask via f32x4 LDS LUT (nibble-indexed additive {0, NEG}) ----
#pragma unroll
    for (int j = 0; j < 4; ++j) {
      unsigned wrd = (j < 2) ? mw.x : mw.y;
      unsigned nib = (wrd >> (((j & 1) << 4) + (l4 << 2))) & 0xFu;
      f32x4 lv = *(const f32x4*)&MLutF[nib << 2];
      sj[j] = sj[j] + lv;
    }

    // ---- lane-local max (max3-friendly nesting); cross-lane only if rescale ----
    float c0 = fmaxf(fmaxf(sj[0][0], sj[0][1]), sj[0][2]);
    float c1 = fmaxf(fmaxf(sj[0][3], sj[1][0]), sj[1][1]);
    float c2 = fmaxf(fmaxf(sj[1][2], sj[1][3]), sj[2][0]);
    float c3 = fmaxf(fmaxf(sj[2][1], sj[2][2]), sj[2][3]);
    float c4 = fmaxf(fmaxf(sj[3][0], sj[3][1]), sj[3][2]);
    float tm = fmaxf(fmaxf(fmaxf(c0, c1), c2), fmaxf(fmaxf(c3, c4), sj[3][3]));

    // defer-max: common path needs NO cross-lane reduce (invariant: all lanes'
    // S <= m_i + 8 => P <= 2^11.5, f16-tree-safe). Reduce only when rescaling.
    if (__any(tm - m_i > 8.0f)) {
      float tr = fmaxf(tm, __shfl_xor(tm, 16));
      tr = fmaxf(tr, __shfl_xor(tr, 32));
      float mnew = fmaxf(m_i, tr);
      float scl = exp2a((m_i - mnew) * L2E);
      l_p *= scl;
      m_i = mnew;
      float sr0 = __shfl(scl, 4 * l4 + 0);
      float sr1 = __shfl(scl, 4 * l4 + 1);
      float sr2 = __shfl(scl, 4 * l4 + 2);
      float sr3 = __shfl(scl, 4 * l4 + 3);
#pragma unroll
      for (int jd = 0; jd < 4; ++jd) {
        accO[jd][0] *= sr0; accO[jd][1] *= sr1;
        accO[jd][2] *= sr2; accO[jd][3] *= sr3;
      }
    }

    // ---- exp (exp2-folded, f32) + pack f16 + 4x b64 P writes + pk l-sum ----
    // P rows are WAVE-PRIVATE: no fence/barrier needed; the compiler's counted
    // lgkmcnt handles the write->read dependency, and V-frag reads (independent
    // of P) are free to hoist into this chain.
    float ml2 = m_i * L2E;
    hf2 acc2;
    acc2.x = (_Float16)0.f;
    acc2.y = (_Float16)0.f;
#pragma unroll
    for (int j = 0; j < 4; ++j) {
      float p0 = exp2a(fmaf(sj[j][0], L2E, -ml2));
      float p1 = exp2a(fmaf(sj[j][1], L2E, -ml2));
      float p2 = exp2a(fmaf(sj[j][2], L2E, -ml2));
      float p3 = exp2a(fmaf(sj[j][3], L2E, -ml2));
      unsigned d0, d1;
      asm("v_cvt_pkrtz_f16_f32 %0, %1, %2" : "=v"(d0) : "v"(p0), "v"(p1));
      asm("v_cvt_pkrtz_f16_f32 %0, %1, %2" : "=v"(d1) : "v"(p2), "v"(p3));
      union { unsigned u; hf2 h; } c0u, c1u;
      c0u.u = d0;
      c1u.u = d1;
      acc2 = acc2 + c0u.h + c1u.h;
      int chunk = ((j << 1) | bhalf) ^ rr7;
      *(u64*)(Pw + prowb + (chunk << 4) + wsub) = (u64)d0 | ((u64)d1 << 32);
    }
    l_p += (float)acc2.x + (float)acc2.y;

    // ---- PV ----
    __builtin_amdgcn_s_setprio(1);
#pragma unroll
    for (int kc = 0; kc < 2; ++kc) {
      int chR = (4 * kc + l4) ^ rr7;
      short8 pa = *(const short8*)(Pw + prowb + (chR << 4));
#pragma unroll
      for (int jd = 0; jd < 4; ++jd) {
        short8 vb = *(const short8*)(VT + swz(l15 + 16 * jd, l4 * 16 + 64 * kc));
        accO[jd] = __builtin_amdgcn_mfma_f32_16x16x32_f16(pa, vb, accO[jd], 0, 0, 0);
      }
    }
    __builtin_amdgcn_s_setprio(0);
    __syncthreads();
    cur ^= 1;
  }

  // epilogue: reduce partial l across l4 groups, redistribute to accO rows
  float lr = l_p;
  lr += __shfl_xor(lr, 16);
  lr += __shfl_xor(lr, 32);
  float inv0 = 1.f / __shfl(lr, 4 * l4 + 0);
  float inv1 = 1.f / __shfl(lr, 4 * l4 + 1);
  float inv2 = 1.f / __shfl(lr, 4 * l4 + 2);
  float inv3 = 1.f / __shfl(lr, 4 * l4 + 3);
  float invs[4] = {inv0, inv1, inv2, inv3};
#pragma unroll
  for (int i = 0; i < 4; ++i) {
    int row = q0 + 16 * w + l4 * 4 + i;
    size_t obase = ((size_t)b * S_ + row) * D_ + h * 64 + l15;
#pragma unroll
    for (int jd = 0; jd < 4; ++jd) xout[obase + 16 * jd] = f2h(accO[jd][i] * invs[i]);
  }
}

extern "C" void kernel_launch(void* const* d_in, const int* in_sizes, int n_in,
                              void* d_out, int out_size, void* d_ws, size_t ws_size,
                              hipStream_t stream) {
  const float* q = (const float*)d_in[0];
  const float* k = (const float*)d_in[1];
  const float* v = (const float*)d_in[2];
  const void* mask = d_in[3];
  const float* wq_w = (const float*)d_in[4];
  const float* wq_b = (const float*)d_in[5];
  const float* wk_w = (const float*)d_in[6];
  const float* wk_b = (const float*)d_in[7];
  const float* wv_w = (const float*)d_in[8];
  const float* wv_b = (const float*)d_in[9];
  const float* wo_w = (const float*)d_in[10];
  const float* wo_b = (const float*)d_in[11];

  const size_t NE = (size_t)B_ * S_ * D_;  // 8M elems
  const size_t NW = (size_t)D_ * D_;       // 1M elems
  const size_t PKB = (size_t)(B_ * S_ * (S_ / 32)) * 4;  // 2MB
  char* ws = (char*)d_ws;
  int* flag = (int*)ws;
  unsigned* pkb = (unsigned*)(ws + 256);
  us* base = (us*)(ws + 256 + PKB);

  dim3 g3(64, 8, 3);
  dim3 g2(64, 8, 2);
  dim3 g1(64, 8, 1);

  const size_t fused_need = 256 + PKB + 6 * NE * 2 + 4 * NW * 2;
  if (ws_size >= fused_need) {
    us* A0 = base;          // q f16 -> later xo
    us* A1 = A0 + NE;       // k f16
    us* A2 = A1 + NE;       // v f16
    us* A3 = A2 + NE;       // qh
    us* A4 = A3 + NE;       // kh
    us* A5 = A4 + NE;       // vt
    us* W0 = A5 + NE;
    us* W1 = W0 + NW;
    us* W2 = W1 + NW;
    us* W3 = W2 + NW;
    prep_w<<<2049, 256, 0, stream>>>(wq_w, wk_w, wv_w, wo_w, W0, W1, W2, W3,
                                     (const int*)mask, flag);
    prep_in<<<2048 + 3 * 4096, 256, 0, stream>>>(mask, flag, pkb, q, k, v, A0, A1, A2);
    gemm2p<2><<<g3, 256, 0, stream>>>(A0, A1, A2, W0, W1, W2, wq_b, wk_b, wv_b,
                                      A3, A4, A5, B_ * S_, D_, D_, 2);
    attn_mfma<<<1024, 512, 0, stream>>>(A3, A4, A5, pkb, A0);  // xo in A0
    gemm2p<0><<<g1, 256, 0, stream>>>(A0, A0, A0, W3, W3, W3, wo_b, wo_b, wo_b,
                                      d_out, d_out, d_out, B_ * S_, D_, D_, -1);
  } else {
    // sequential 5-buffer plan
    us* A0 = base;
    us* A1 = A0 + NE;
    us* A2 = A1 + NE;  // qh
    us* A3 = A2 + NE;  // kh
    us* A4 = A3 + NE;  // vt
    us* W0 = A4 + NE;
    us* W1 = W0 + NW;
    us* W2 = W1 + NW;
    us* W3 = W2 + NW;
    detect_mask_kernel<<<1, 64, 0, stream>>>((const int*)mask, flag);
    pack_mask<<<2048, 256, 0, stream>>>(mask, flag, pkb);
    prep_w<<<2048, 256, 0, stream>>>(wq_w, wk_w, wv_w, wo_w, W0, W1, W2, W3,
                                     (const int*)mask, flag);
    cvt_f16x3<<<2 * 4096, 256, 0, stream>>>(q, k, nullptr, A0, A1, nullptr);
    gemm2p<2><<<g2, 256, 0, stream>>>(A0, A1, nullptr, W0, W1, nullptr, wq_b, wk_b, nullptr,
                                      A2, A3, nullptr, B_ * S_, D_, D_, -1);
    cvt_f16x3<<<4096, 256, 0, stream>>>(v, nullptr, nullptr, A0, nullptr, nullptr);
    gemm2p<2><<<g1, 256, 0, stream>>>(A0, nullptr, nullptr, W2, nullptr, nullptr,
                                      wv_b, nullptr, nullptr, A4, nullptr, nullptr,
                                      B_ * S_, D_, D_, 0);  // V -> vt (transposed)
    attn_mfma<<<1024, 512, 0, stream>>>(A2, A3, A4, pkb, A0);  // xo in A0
    gemm2p<0><<<g1, 256, 0, stream>>>(A0, nullptr, nullptr, W3, nullptr, nullptr,
                                      wo_b, nullptr, nullptr, d_out, nullptr, nullptr,
                                      B_ * S_, D_, D_, -1);
  }
}